// Round 18
// baseline (126.582 us; speedup 1.0000x reference)
//
#include <hip/hip_runtime.h>

#define Bn 512
#define Kn 160
#define Hn 256
#define ALPHA 0.5f
#define MAX_SPAN 30
#define L_FGW 0.1f
#define L_SPAN 0.5f
#define L_CONS 0.3f
#define KP 16
#define NP 10

typedef __bf16 bf16x8 __attribute__((ext_vector_type(8)));
typedef float f32x16 __attribute__((ext_vector_type(16)));
typedef float f32x4v __attribute__((ext_vector_type(4)));

// Phase A-D scratch and fgw scratch share one LDS union; p/q live OUTSIDE
// the union (E's gw1/gw2 fusion reads them during MFMA staging).
struct PhS {
  float prow[160][41];          // p row-partials (pad 41)
  float qcol[16][160];          // q partials per rm
  float vcol[16][160];          // vsc partials per rm
  float vscsh[160];
  float esh[160], eeh[160], vssh[160], veh[160];   // QA logits in-LDS
  float wsh[16];
  float bv[256];
  int bidx[256];
  int pspe[2];
};
struct FgS {
  __bf16 sDen[2][2][Kn][8];
  __bf16 sG[2][2][Kn][8];
  __bf16 sGT[2][2][Kn][8];
  __bf16 sVT[2][2][Kn][8];
  float red[48];
};

// raw barrier: LDS drained, global loads stay in flight (no vmcnt drain)
__device__ __forceinline__ void wg_barrier() {
  asm volatile("s_waitcnt lgkmcnt(0)" ::: "memory");
  __builtin_amdgcn_s_barrier();
  __builtin_amdgcn_sched_barrier(0);
}

// ---- one block per batch: fused gamma/M + QA streams -> losses -> fgw(+gw1/gw2) ----
__global__ __launch_bounds__(1024, 4) void mega_k(
    const float* __restrict__ en, const float* __restrict__ vi,
    const float* __restrict__ w_s, const float* __restrict__ b_s,
    const float* __restrict__ w_e, const float* __restrict__ b_e,
    const float* __restrict__ gam, const float* __restrict__ M,
    const float* __restrict__ Den, const float* __restrict__ Dvi,
    const int* __restrict__ enst, const int* __restrict__ enen,
    float* __restrict__ sp1) {
  __shared__ __align__(16) char shraw[sizeof(PhS)];
  __shared__ float psh_s[160];
  __shared__ float qsh_s[160];
  PhS& S = *(PhS*)shraw;
  FgS& F = *(FgS*)shraw;
  int b = blockIdx.x;
  int tid = threadIdx.x;
  int wv = tid >> 6, lane = tid & 63;
  const float* gam_b = gam + (size_t)b * 25600;
  const float* m_b   = M   + (size_t)b * 25600;
  const float* den_b = Den + (size_t)b * 25600;
  const float* dvi_b = Dvi + (size_t)b * 25600;
  int s0 = enst[b], e0 = enen[b];
  int s = min(max(s0, 0), Kn - 1);
  int e = max(s, min(max(e0, 0), Kn - 1));
  bool actA = tid < 640;
  int rm = tid / 40, c = tid - 40 * rm;    // A layout (uniform 16-row slabs)

  // ---- Phase A+C fused: gamma+M stats and QA logits in one 10-iter loop ----
  float4 ws4 = *(const float4*)(w_s + lane * 4);
  float4 we4 = *(const float4*)(w_e + lane * 4);
  float bs0 = b_s[0], be0 = b_e[0];
  const float* en_b = en + (size_t)b * 40960;
  const float* vi_b = vi + (size_t)b * 40960;
  float q4[4] = {0.f,0.f,0.f,0.f}, v4[4] = {0.f,0.f,0.f,0.f};
  float wloc = 0.f;
  #pragma unroll
  for (int it = 0; it < 10; ++it) {
    int crow = wv * 10 + it;     // C: one row per wave per iter
    f32x4v ev = __builtin_nontemporal_load((const f32x4v*)(en_b + (size_t)crow * 256 + lane * 4));
    f32x4v vv = __builtin_nontemporal_load((const f32x4v*)(vi_b + (size_t)crow * 256 + lane * 4));
    if (actA) {
      int r = 16 * it + rm;      // A: uniform 16-row slab
      float4 g = *(const float4*)(gam_b + (size_t)r * 160 + 4 * c);
      f32x4v m = __builtin_nontemporal_load((const f32x4v*)(m_b + (size_t)r * 160 + 4 * c));
      wloc += m[0]*g.x + m[1]*g.y + m[2]*g.z + m[3]*g.w;
      S.prow[r][c] = g.x + g.y + g.z + g.w;
      q4[0]+=g.x; q4[1]+=g.y; q4[2]+=g.z; q4[3]+=g.w;
      float f = (r >= s && r <= e) ? 1.f : 0.f;
      v4[0]+=f*g.x; v4[1]+=f*g.y; v4[2]+=f*g.z; v4[3]+=f*g.w;
    }
    float a0 = ev[0]*ws4.x + ev[1]*ws4.y + ev[2]*ws4.z + ev[3]*ws4.w;
    float a1 = ev[0]*we4.x + ev[1]*we4.y + ev[2]*we4.z + ev[3]*we4.w;
    float a2 = vv[0]*ws4.x + vv[1]*ws4.y + vv[2]*ws4.z + vv[3]*ws4.w;
    float a3 = vv[0]*we4.x + vv[1]*we4.y + vv[2]*we4.z + vv[3]*we4.w;
    #pragma unroll
    for (int o = 32; o; o >>= 1) {
      a0 += __shfl_xor(a0, o); a1 += __shfl_xor(a1, o);
      a2 += __shfl_xor(a2, o); a3 += __shfl_xor(a3, o);
    }
    if (lane == 0) {
      S.esh[crow] = a0 + bs0;  S.eeh[crow] = a1 + be0;
      S.vssh[crow] = a2 + bs0; S.veh[crow] = a3 + be0;
    }
  }
  if (actA) {
    #pragma unroll
    for (int j = 0; j < 4; ++j) { S.qcol[rm][4*c+j] = q4[j]; S.vcol[rm][4*c+j] = v4[j]; }
  }
  #pragma unroll
  for (int o = 32; o; o >>= 1) wloc += __shfl_xor(wloc, o);
  if (lane == 0) S.wsh[wv] = wloc;
  __syncthreads();
  if (tid < 160) {
    float sp = 0.f;
    #pragma unroll 8
    for (int c2 = 0; c2 < 40; ++c2) sp += S.prow[tid][c2];
    psh_s[tid] = sp;
    float sq = 0.f, sv = 0.f;
    #pragma unroll 4
    for (int k = 0; k < 16; ++k) { sq += S.qcol[k][tid]; sv += S.vcol[k][tid]; }
    qsh_s[tid] = sq;
    S.vscsh[tid] = sv;
  }
  __syncthreads();

  // ---- Phase D: span argmax + QA CE + KL + span CE -> sp1[0..6] ----
  float best = -1e30f;
  int bfl = 0x7fffffff;
  if (tid < 160) {
    float vsi = S.vscsh[tid];
    int hi = min(tid + MAX_SPAN, Kn - 1);
    for (int ei = tid; ei <= hi; ++ei) {
      float v = vsi + S.vscsh[ei];
      if (v > best) { best = v; bfl = tid * Kn + ei; }  // first-max (np.argmax)
    }
  }
  if (tid < 256) { S.bv[tid] = best; S.bidx[tid] = bfl; }
  for (int st = 128; st > 0; st >>= 1) {
    __syncthreads();
    if (tid < st) {
      float v2 = S.bv[tid + st]; int i2 = S.bidx[tid + st];
      if (v2 > S.bv[tid] || (v2 == S.bv[tid] && i2 < S.bidx[tid])) { S.bv[tid] = v2; S.bidx[tid] = i2; }
    }
  }
  if (tid == 0) {
    int fl = S.bidx[0];
    int ps = fl / Kn, pe = fl - (fl / Kn) * Kn;
    if (s0 == 0 && e0 == 0) { ps = 0; pe = 0; }
    S.pspe[0] = ps; S.pspe[1] = pe;
    float sw = 0.f;
    #pragma unroll
    for (int i = 0; i < 16; ++i) sw += S.wsh[i];
    sp1[(size_t)b * 12 + 4] = sw;
  }
  __syncthreads();
  if (wv == 0) {
    float xes[3], xee[3], xvs[3], xve[3];
    #pragma unroll
    for (int j = 0; j < 3; ++j) {
      int idx = lane + 64 * j;
      bool val = idx < Kn;
      xes[j] = val ? S.esh[idx] : -1e30f;
      xee[j] = val ? S.eeh[idx] : -1e30f;
      xvs[j] = val ? S.vssh[idx] : -1e30f;
      xve[j] = val ? S.veh[idx] : -1e30f;
    }
    auto wlse = [&](float x0, float x1, float x2) -> float {
      float m = fmaxf(fmaxf(x0, x1), x2);
      #pragma unroll
      for (int o = 32; o; o >>= 1) m = fmaxf(m, __shfl_xor(m, o));
      float su = expf(x0 - m) + expf(x1 - m) + expf(x2 - m);
      #pragma unroll
      for (int o = 32; o; o >>= 1) su += __shfl_xor(su, o);
      return m + logf(su);
    };
    float l_es = wlse(xes[0], xes[1], xes[2]);
    float l_ee = wlse(xee[0], xee[1], xee[2]);
    float l_vs = wlse(xvs[0], xvs[1], xvs[2]);
    float l_ve = wlse(xve[0], xve[1], xve[2]);
    float lT_es = wlse(xes[0]*0.5f, xes[1]*0.5f, xes[2]*0.5f);
    float lT_ee = wlse(xee[0]*0.5f, xee[1]*0.5f, xee[2]*0.5f);
    float lT_vs = wlse(xvs[0]*0.5f, xvs[1]*0.5f, xvs[2]*0.5f);
    float lT_ve = wlse(xve[0]*0.5f, xve[1]*0.5f, xve[2]*0.5f);
    float kls = 0.f, kle = 0.f;
    #pragma unroll
    for (int j = 0; j < 3; ++j) {
      int idx = lane + 64 * j;
      if (idx < Kn) {
        float aa = xes[j]*0.5f - lT_es;
        float bb = xvs[j]*0.5f - lT_vs;
        kls += expf(aa) * (aa - bb);
        float cc = xee[j]*0.5f - lT_ee;
        float dd = xve[j]*0.5f - lT_ve;
        kle += expf(cc) * (cc - dd);
      }
    }
    #pragma unroll
    for (int o = 32; o; o >>= 1) { kls += __shfl_xor(kls, o); kle += __shfl_xor(kle, o); }
    if (lane == 0) {
      int sl = min(max(s0, 0), Kn - 1);
      int el = min(max(e0, 0), Kn - 1);
      float* o = sp1 + (size_t)b * 12;
      o[0] = l_es - S.esh[sl];
      o[1] = l_ee - S.eeh[el];
      o[2] = kls;
      o[3] = kle;
      bool answerable = (s0 > 0) || (e0 > 0);
      float ce = 0.5f * ((l_vs - S.vssh[S.pspe[0]]) + (l_ve - S.veh[S.pspe[1]]));
      o[5] = answerable ? ce : 0.f;
      o[6] = answerable ? 1.f : 0.f;
    }
  }
  __syncthreads();   // all Phase-D LDS reads done before fgw overwrites the union

  // ---- Phase E: fgw gw3 via MFMA; gw1/gw2 fused into the staging loads.
  // Single reg-set + dbuf LDS pipeline (panel p+1 loads issued before mf(p)).
  bool rm0 = tid < 640;
  const float* s0p;
  __bf16 *d0[2];
  bool isDen0 = false, isVT0 = false;
  float w0r = 0.f;
  const float* wp0 = psh_s;     // weight vector base for slot0 fusion
  if (rm0) {
    int op = tid >= 320 ? 1 : 0;
    int fr = tid - 320 * op;
    int cc = fr >= 160 ? 1 : 0;
    int r = fr - 160 * cc;
    s0p = (op ? gam_b : den_b) + (size_t)r * 160 + 8 * cc;
    d0[0] = op ? &F.sG[0][cc][r][0] : &F.sDen[0][cc][r][0];
    d0[1] = op ? &F.sG[1][cc][r][0] : &F.sDen[1][cc][r][0];
    if (!op) { isDen0 = true; w0r = psh_s[r]; wp0 = psh_s + 8 * cc; }
  } else {
    int f3 = tid - 640;
    int op = f3 >= 320 ? 1 : 0;
    int f4 = f3 - 320 * op;
    int cc = f4 >= 160 ? 1 : 0;
    int j = f4 - 160 * cc;
    s0p = (op ? dvi_b : gam_b) + (size_t)(8 * cc) * 160 + j;
    d0[0] = op ? &F.sVT[0][cc][j][0] : &F.sGT[0][cc][j][0];
    d0[1] = op ? &F.sVT[1][cc][j][0] : &F.sGT[1][cc][j][0];
    if (op) { isVT0 = true; w0r = qsh_s[j]; wp0 = qsh_s + 8 * cc; }
  }
  bool act1 = tid < 256;
  int f5 = tid + 64;
  int cc1 = f5 >= 160 ? 1 : 0;
  int j1 = f5 - 160 * cc1;
  const float* s1p = dvi_b + (size_t)(8 * cc1) * 160 + j1;
  __bf16* d1[2] = { &F.sVT[0][cc1][j1][0], &F.sVT[1][cc1][j1][0] };
  float w1r = act1 ? qsh_s[j1] : 0.f;
  const float* wp1 = qsh_s + 8 * cc1;
  float gw1a = 0.f, gw2a = 0.f;

  float v0[8], v1[8];
  auto loadP = [&](int p) {
    if (rm0) {
      const float* sp = s0p + p * KP;
      float4 x = *(const float4*)sp;
      float4 y = *(const float4*)(sp + 4);
      v0[0]=x.x; v0[1]=x.y; v0[2]=x.z; v0[3]=x.w;
      v0[4]=y.x; v0[5]=y.y; v0[6]=y.z; v0[7]=y.w;
    } else {
      const float* sp = s0p + (size_t)p * KP * 160;
      #pragma unroll
      for (int e2 = 0; e2 < 8; ++e2) v0[e2] = sp[(size_t)e2 * 160];
    }
    if (act1) {
      const float* sp = s1p + (size_t)p * KP * 160;
      #pragma unroll
      for (int e2 = 0; e2 < 8; ++e2) v1[e2] = sp[(size_t)e2 * 160];
    }
  };
  auto wrP = [&](int p) {            // convert+LDS-write + gw1/gw2 fusion
    int db = p & 1;
    if (isDen0 | isVT0) {
      const float* pw = wp0 + 16 * p;
      float t = 0.f;
      #pragma unroll
      for (int e2 = 0; e2 < 8; ++e2) t += v0[e2] * v0[e2] * pw[e2];
      if (isDen0) gw1a += w0r * t; else gw2a += w0r * t;
    }
    bf16x8 wv2;
    #pragma unroll
    for (int e2 = 0; e2 < 8; ++e2) wv2[e2] = (__bf16)v0[e2];
    *(bf16x8*)d0[db] = wv2;
    if (act1) {
      const float* qw = wp1 + 16 * p;
      float t = 0.f;
      #pragma unroll
      for (int e2 = 0; e2 < 8; ++e2) t += v1[e2] * v1[e2] * qw[e2];
      gw2a += w1r * t;
      bf16x8 wv3;
      #pragma unroll
      for (int e2 = 0; e2 < 8; ++e2) wv3[e2] = (__bf16)v1[e2];
      *(bf16x8*)d1[db] = wv3;
    }
  };

  int ra = lane & 31, cc2 = lane >> 5;
  int t0 = wv;                 // 0..15, always < 25
  int ti0 = t0 / 5, tj0 = t0 - 5 * (t0 / 5);
  int rowa0 = ti0 * 32 + ra, rowb0 = tj0 * 32 + ra;
  int t1 = wv + 16;
  bool val1t = t1 < 25;
  int ti1 = t1 / 5, tj1 = t1 - 5 * (t1 / 5);
  int rowa1 = ti1 * 32 + ra, rowb1 = tj1 * 32 + ra;
  f32x16 acc10 = {}, acc20 = {}, acc11 = {}, acc21 = {};
  auto mf = [&](int BUF) {
    {
      bf16x8 a1 = *(const bf16x8*)&F.sDen[BUF][cc2][rowa0][0];
      bf16x8 b1 = *(const bf16x8*)&F.sGT[BUF][cc2][rowb0][0];
      bf16x8 a2 = *(const bf16x8*)&F.sG[BUF][cc2][rowa0][0];
      bf16x8 b2 = *(const bf16x8*)&F.sVT[BUF][cc2][rowb0][0];
      acc10 = __builtin_amdgcn_mfma_f32_32x32x16_bf16(a1, b1, acc10, 0, 0, 0);
      acc20 = __builtin_amdgcn_mfma_f32_32x32x16_bf16(a2, b2, acc20, 0, 0, 0);
    }
    if (val1t) {
      bf16x8 a1 = *(const bf16x8*)&F.sDen[BUF][cc2][rowa1][0];
      bf16x8 b1 = *(const bf16x8*)&F.sGT[BUF][cc2][rowb1][0];
      bf16x8 a2 = *(const bf16x8*)&F.sG[BUF][cc2][rowa1][0];
      bf16x8 b2 = *(const bf16x8*)&F.sVT[BUF][cc2][rowb1][0];
      acc11 = __builtin_amdgcn_mfma_f32_32x32x16_bf16(a1, b1, acc11, 0, 0, 0);
      acc21 = __builtin_amdgcn_mfma_f32_32x32x16_bf16(a2, b2, acc21, 0, 0, 0);
    }
  };

  loadP(0);
  wrP(0);
  __syncthreads();
  for (int p = 0; p < NP; ++p) {
    if (p + 1 < NP) loadP(p + 1);    // issue next-panel loads early
    mf(p & 1);                       // consume current panel
    if (p + 1 < NP) wrP(p + 1);      // stage next panel (other buffer)
    wg_barrier();
  }
  float g3 = 0.f;
  #pragma unroll
  for (int r2 = 0; r2 < 16; ++r2) g3 += acc10[r2] * acc20[r2];
  if (val1t) {
    #pragma unroll
    for (int r2 = 0; r2 < 16; ++r2) g3 += acc11[r2] * acc21[r2];
  }
  #pragma unroll
  for (int o = 32; o; o >>= 1) {
    g3 += __shfl_xor(g3, o);
    gw1a += __shfl_xor(gw1a, o);
    gw2a += __shfl_xor(gw2a, o);
  }
  if (lane == 0) { F.red[wv] = g3; F.red[16 + wv] = gw1a; F.red[32 + wv] = gw2a; }
  __syncthreads();
  if (tid == 0) {
    float s3 = 0.f, s1 = 0.f, s2 = 0.f;
    #pragma unroll
    for (int i = 0; i < 16; ++i) { s3 += F.red[i]; s1 += F.red[16 + i]; s2 += F.red[32 + i]; }
    float* o = sp1 + (size_t)b * 12;
    o[7] = s1; o[8] = s2; o[9] = s3;
  }
}

// ---- final reduction over batches ----
__global__ __launch_bounds__(512) void finalize_k(
    const float* __restrict__ sp1, float* __restrict__ out) {
  __shared__ float red[8][10];
  int tid = threadIdx.x;
  int wid = tid >> 6, lane = tid & 63;
  float v[10];
  const float* a = sp1 + (size_t)tid * 12;
  #pragma unroll
  for (int i = 0; i < 10; ++i) v[i] = a[i];
  #pragma unroll
  for (int i = 0; i < 10; ++i) {
    float s = v[i];
    #pragma unroll
    for (int o = 32; o; o >>= 1) s += __shfl_xor(s, o);
    v[i] = s;
  }
  if (lane == 0) {
    #pragma unroll
    for (int i = 0; i < 10; ++i) red[wid][i] = v[i];
  }
  __syncthreads();
  if (tid == 0) {
    float t[10];
    #pragma unroll
    for (int i = 0; i < 10; ++i) {
      float s = 0.f;
      #pragma unroll
      for (int w2 = 0; w2 < 8; ++w2) s += red[w2][i];
      t[i] = s;
    }
    float ce_s = t[0], ce_e = t[1], kls = t[2], kle = t[3];
    float w = t[4], spn = t[5], nans = t[6];
    float gw1 = t[7], gw2 = t[8], gw3 = t[9];
    float l_qa = (ce_s + ce_e) / (2.f * Bn);
    float l_fgw = (ALPHA * (gw1 + gw2 - 2.f * gw3) + (1.f - ALPHA) * w) / Bn;
    float l_span = (nans > 0.f) ? spn / fmaxf(nans, 1.f) : 0.f;
    float l_cons = 2.f * (kls + kle) / Bn;  // T^2 * ((kls+kle)/B) / 2 with T=2
    float total = l_qa + L_FGW * l_fgw + L_SPAN * l_span + L_CONS * l_cons;
    out[0] = total; out[1] = l_qa; out[2] = l_fgw; out[3] = l_span; out[4] = l_cons;
  }
}

extern "C" void kernel_launch(void* const* d_in, const int* in_sizes, int n_in,
                              void* d_out, int out_size, void* d_ws, size_t ws_size,
                              hipStream_t stream) {
  const float* en  = (const float*)d_in[0];
  const float* vi  = (const float*)d_in[1];
  const float* gam = (const float*)d_in[2];
  const float* Den = (const float*)d_in[3];
  const float* Dvi = (const float*)d_in[4];
  const float* M   = (const float*)d_in[5];
  const int* enst  = (const int*)d_in[6];
  const int* enen  = (const int*)d_in[7];
  const float* w_s = (const float*)d_in[8];
  const float* b_s = (const float*)d_in[9];
  const float* w_e = (const float*)d_in[10];
  const float* b_e = (const float*)d_in[11];
  float* sp1 = (float*)d_ws;               // 512*12 per-batch partials
  float* out = (float*)d_out;

  mega_k<<<Bn, 1024, 0, stream>>>(en, vi, w_s, b_s, w_e, b_e, gam, M, Den, Dvi,
                                  enst, enen, sp1);
  finalize_k<<<1, 512, 0, stream>>>(sp1, out);
}

// Round 19
// 118.079 us; speedup vs baseline: 1.0720x; 1.0720x over previous
//
#include <hip/hip_runtime.h>

#define Bn 512
#define Kn 160
#define Hn 256
#define ALPHA 0.5f
#define MAX_SPAN 30
#define L_FGW 0.1f
#define L_SPAN 0.5f
#define L_CONS 0.3f
#define KP 16
#define NP 10

typedef __bf16 bf16x8 __attribute__((ext_vector_type(8)));
typedef float f32x16 __attribute__((ext_vector_type(16)));
typedef float f32x4v __attribute__((ext_vector_type(4)));

// Phase A-D scratch and fgw scratch share one LDS union; p/q live OUTSIDE
// the union (E's gw1/gw2 fusion reads them during MFMA staging).
struct PhS {
  float prow[160][41];          // p row-partials (pad 41)
  float qcol[16][160];          // q partials per rm
  float vcol[16][160];          // vsc partials per rm
  float vscsh[160];
  float esh[160], eeh[160], vssh[160], veh[160];   // QA logits in-LDS
  float wsh[16];
  float bv[256];
  int bidx[256];
  int pspe[2];
};
struct FgS {
  __bf16 sDen[2][2][Kn][8];
  __bf16 sG[2][2][Kn][8];
  __bf16 sGT[2][2][Kn][8];
  __bf16 sVT[2][2][Kn][8];
  float red[48];
};

// raw barrier: LDS drained, global loads stay in flight (no vmcnt drain)
__device__ __forceinline__ void wg_barrier() {
  asm volatile("s_waitcnt lgkmcnt(0)" ::: "memory");
  __builtin_amdgcn_s_barrier();
  __builtin_amdgcn_sched_barrier(0);
}

// ---- one block per batch: fused gamma/M + QA streams (+D prefetch) ->
//      losses -> fgw(+gw1/gw2 fused into staging) ----
__global__ __launch_bounds__(1024, 4) void mega_k(
    const float* __restrict__ en, const float* __restrict__ vi,
    const float* __restrict__ w_s, const float* __restrict__ b_s,
    const float* __restrict__ w_e, const float* __restrict__ b_e,
    const float* __restrict__ gam, const float* __restrict__ M,
    const float* __restrict__ Den, const float* __restrict__ Dvi,
    const int* __restrict__ enst, const int* __restrict__ enen,
    float* __restrict__ sp1) {
  __shared__ __align__(16) char shraw[sizeof(PhS)];
  __shared__ float psh_s[160];
  __shared__ float qsh_s[160];
  PhS& S = *(PhS*)shraw;
  FgS& F = *(FgS*)shraw;
  int b = blockIdx.x;
  int tid = threadIdx.x;
  int wv = tid >> 6, lane = tid & 63;
  const float* gam_b = gam + (size_t)b * 25600;
  const float* m_b   = M   + (size_t)b * 25600;
  const float* den_b = Den + (size_t)b * 25600;
  const float* dvi_b = Dvi + (size_t)b * 25600;
  int s0 = enst[b], e0 = enen[b];
  int s = min(max(s0, 0), Kn - 1);
  int e = max(s, min(max(e0, 0), Kn - 1));
  bool actA = tid < 640;
  int rm = tid / 40, c = tid - 40 * rm;    // A layout (uniform 16-row slabs)

  // ---- Phase A+C fused: gamma+M stats, QA logits, and D_en/D_vi L2/L3
  //      prefetch (E reads them later; issue loads on the idle memory pipe).
  float4 ws4 = *(const float4*)(w_s + lane * 4);
  float4 we4 = *(const float4*)(w_e + lane * 4);
  float bs0 = b_s[0], be0 = b_e[0];
  const float* en_b = en + (size_t)b * 40960;
  const float* vi_b = vi + (size_t)b * 40960;
  float q4[4] = {0.f,0.f,0.f,0.f}, v4[4] = {0.f,0.f,0.f,0.f};
  float wloc = 0.f;
  #pragma unroll
  for (int it = 0; it < 10; ++it) {
    int crow = wv * 10 + it;     // C: one row per wave per iter
    f32x4v ev = __builtin_nontemporal_load((const f32x4v*)(en_b + (size_t)crow * 256 + lane * 4));
    f32x4v vv = __builtin_nontemporal_load((const f32x4v*)(vi_b + (size_t)crow * 256 + lane * 4));
    if (actA) {
      int r = 16 * it + rm;      // A: uniform 16-row slab
      float4 g = *(const float4*)(gam_b + (size_t)r * 160 + 4 * c);
      f32x4v m = __builtin_nontemporal_load((const f32x4v*)(m_b + (size_t)r * 160 + 4 * c));
      // D prefetch: same element E will read; keep live so dwordx4 isn't DCE'd
      float4 dp = *(const float4*)(den_b + (size_t)r * 160 + 4 * c);
      float4 vp = *(const float4*)(dvi_b + (size_t)r * 160 + 4 * c);
      asm volatile("" :: "v"(dp.x), "v"(dp.y), "v"(dp.z), "v"(dp.w),
                        "v"(vp.x), "v"(vp.y), "v"(vp.z), "v"(vp.w));
      wloc += m[0]*g.x + m[1]*g.y + m[2]*g.z + m[3]*g.w;
      S.prow[r][c] = g.x + g.y + g.z + g.w;
      q4[0]+=g.x; q4[1]+=g.y; q4[2]+=g.z; q4[3]+=g.w;
      float f = (r >= s && r <= e) ? 1.f : 0.f;
      v4[0]+=f*g.x; v4[1]+=f*g.y; v4[2]+=f*g.z; v4[3]+=f*g.w;
    }
    float a0 = ev[0]*ws4.x + ev[1]*ws4.y + ev[2]*ws4.z + ev[3]*ws4.w;
    float a1 = ev[0]*we4.x + ev[1]*we4.y + ev[2]*we4.z + ev[3]*we4.w;
    float a2 = vv[0]*ws4.x + vv[1]*ws4.y + vv[2]*ws4.z + vv[3]*ws4.w;
    float a3 = vv[0]*we4.x + vv[1]*we4.y + vv[2]*we4.z + vv[3]*we4.w;
    #pragma unroll
    for (int o = 32; o; o >>= 1) {
      a0 += __shfl_xor(a0, o); a1 += __shfl_xor(a1, o);
      a2 += __shfl_xor(a2, o); a3 += __shfl_xor(a3, o);
    }
    if (lane == 0) {
      S.esh[crow] = a0 + bs0;  S.eeh[crow] = a1 + be0;
      S.vssh[crow] = a2 + bs0; S.veh[crow] = a3 + be0;
    }
  }
  if (actA) {
    #pragma unroll
    for (int j = 0; j < 4; ++j) { S.qcol[rm][4*c+j] = q4[j]; S.vcol[rm][4*c+j] = v4[j]; }
  }
  #pragma unroll
  for (int o = 32; o; o >>= 1) wloc += __shfl_xor(wloc, o);
  if (lane == 0) S.wsh[wv] = wloc;
  __syncthreads();
  if (tid < 160) {
    float sp = 0.f;
    #pragma unroll 8
    for (int c2 = 0; c2 < 40; ++c2) sp += S.prow[tid][c2];
    psh_s[tid] = sp;
    float sq = 0.f, sv = 0.f;
    #pragma unroll 4
    for (int k = 0; k < 16; ++k) { sq += S.qcol[k][tid]; sv += S.vcol[k][tid]; }
    qsh_s[tid] = sq;
    S.vscsh[tid] = sv;
  }
  __syncthreads();

  // ---- Phase D: span argmax + QA CE + KL + span CE -> sp1[0..6] ----
  float best = -1e30f;
  int bfl = 0x7fffffff;
  if (tid < 160) {
    float vsi = S.vscsh[tid];
    int hi = min(tid + MAX_SPAN, Kn - 1);
    for (int ei = tid; ei <= hi; ++ei) {
      float v = vsi + S.vscsh[ei];
      if (v > best) { best = v; bfl = tid * Kn + ei; }  // first-max (np.argmax)
    }
  }
  if (tid < 256) { S.bv[tid] = best; S.bidx[tid] = bfl; }
  for (int st = 128; st > 0; st >>= 1) {
    __syncthreads();
    if (tid < st) {
      float v2 = S.bv[tid + st]; int i2 = S.bidx[tid + st];
      if (v2 > S.bv[tid] || (v2 == S.bv[tid] && i2 < S.bidx[tid])) { S.bv[tid] = v2; S.bidx[tid] = i2; }
    }
  }
  if (tid == 0) {
    int fl = S.bidx[0];
    int ps = fl / Kn, pe = fl - (fl / Kn) * Kn;
    if (s0 == 0 && e0 == 0) { ps = 0; pe = 0; }
    S.pspe[0] = ps; S.pspe[1] = pe;
    float sw = 0.f;
    #pragma unroll
    for (int i = 0; i < 16; ++i) sw += S.wsh[i];
    sp1[(size_t)b * 12 + 4] = sw;
  }
  __syncthreads();
  if (wv == 0) {
    float xes[3], xee[3], xvs[3], xve[3];
    #pragma unroll
    for (int j = 0; j < 3; ++j) {
      int idx = lane + 64 * j;
      bool val = idx < Kn;
      xes[j] = val ? S.esh[idx] : -1e30f;
      xee[j] = val ? S.eeh[idx] : -1e30f;
      xvs[j] = val ? S.vssh[idx] : -1e30f;
      xve[j] = val ? S.veh[idx] : -1e30f;
    }
    auto wlse = [&](float x0, float x1, float x2) -> float {
      float m = fmaxf(fmaxf(x0, x1), x2);
      #pragma unroll
      for (int o = 32; o; o >>= 1) m = fmaxf(m, __shfl_xor(m, o));
      float su = expf(x0 - m) + expf(x1 - m) + expf(x2 - m);
      #pragma unroll
      for (int o = 32; o; o >>= 1) su += __shfl_xor(su, o);
      return m + logf(su);
    };
    float l_es = wlse(xes[0], xes[1], xes[2]);
    float l_ee = wlse(xee[0], xee[1], xee[2]);
    float l_vs = wlse(xvs[0], xvs[1], xvs[2]);
    float l_ve = wlse(xve[0], xve[1], xve[2]);
    float lT_es = wlse(xes[0]*0.5f, xes[1]*0.5f, xes[2]*0.5f);
    float lT_ee = wlse(xee[0]*0.5f, xee[1]*0.5f, xee[2]*0.5f);
    float lT_vs = wlse(xvs[0]*0.5f, xvs[1]*0.5f, xvs[2]*0.5f);
    float lT_ve = wlse(xve[0]*0.5f, xve[1]*0.5f, xve[2]*0.5f);
    float kls = 0.f, kle = 0.f;
    #pragma unroll
    for (int j = 0; j < 3; ++j) {
      int idx = lane + 64 * j;
      if (idx < Kn) {
        float aa = xes[j]*0.5f - lT_es;
        float bb = xvs[j]*0.5f - lT_vs;
        kls += expf(aa) * (aa - bb);
        float cc = xee[j]*0.5f - lT_ee;
        float dd = xve[j]*0.5f - lT_ve;
        kle += expf(cc) * (cc - dd);
      }
    }
    #pragma unroll
    for (int o = 32; o; o >>= 1) { kls += __shfl_xor(kls, o); kle += __shfl_xor(kle, o); }
    if (lane == 0) {
      int sl = min(max(s0, 0), Kn - 1);
      int el = min(max(e0, 0), Kn - 1);
      float* o = sp1 + (size_t)b * 12;
      o[0] = l_es - S.esh[sl];
      o[1] = l_ee - S.eeh[el];
      o[2] = kls;
      o[3] = kle;
      bool answerable = (s0 > 0) || (e0 > 0);
      float ce = 0.5f * ((l_vs - S.vssh[S.pspe[0]]) + (l_ve - S.veh[S.pspe[1]]));
      o[5] = answerable ? ce : 0.f;
      o[6] = answerable ? 1.f : 0.f;
    }
  }
  __syncthreads();   // all Phase-D LDS reads done before fgw overwrites the union

  // ---- Phase E: fgw gw3 via MFMA; gw1/gw2 fused into the staging loads
  // (each D_en/D_vi element passes through exactly once, fp32, pre-bf16).
  bool rm0 = tid < 640;
  const float* s0p;
  __bf16 *d00, *d01;
  bool isDen0 = false, isVT0 = false;
  float w0r = 0.f;       // p[r] for D_en threads, q[j] for slot0-VT threads
  int cb0 = 0;           // 8*cc: column base within panel
  if (rm0) {
    int op = tid >= 320 ? 1 : 0;
    int fr = tid - 320 * op;
    int cc = fr >= 160 ? 1 : 0;
    int r = fr - 160 * cc;
    s0p = (op ? gam_b : den_b) + (size_t)r * 160 + 8 * cc;
    d00 = op ? &F.sG[0][cc][r][0] : &F.sDen[0][cc][r][0];
    d01 = op ? &F.sG[1][cc][r][0] : &F.sDen[1][cc][r][0];
    if (!op) { isDen0 = true; w0r = psh_s[r]; cb0 = 8 * cc; }
  } else {
    int f3 = tid - 640;
    int op = f3 >= 320 ? 1 : 0;
    int f4 = f3 - 320 * op;
    int cc = f4 >= 160 ? 1 : 0;
    int j = f4 - 160 * cc;
    s0p = (op ? dvi_b : gam_b) + (size_t)(8 * cc) * 160 + j;
    d00 = op ? &F.sVT[0][cc][j][0] : &F.sGT[0][cc][j][0];
    d01 = op ? &F.sVT[1][cc][j][0] : &F.sGT[1][cc][j][0];
    if (op) { isVT0 = true; w0r = qsh_s[j]; cb0 = 8 * cc; }
  }
  bool act1 = tid < 256;
  int f5 = tid + 64;
  int cc1 = f5 >= 160 ? 1 : 0;
  int j1 = f5 - 160 * cc1;
  const float* s1p = dvi_b + (size_t)(8 * cc1) * 160 + j1;
  __bf16* d10 = &F.sVT[0][cc1][j1][0];
  __bf16* d11 = &F.sVT[1][cc1][j1][0];
  float w1r = act1 ? qsh_s[j1] : 0.f;
  int cb1 = 8 * cc1;
  float gw1a = 0.f, gw2a = 0.f;

  float vA0[8], vA1[8], vB0[8], vB1[8];
  auto load0 = [&](int p, float* v) {
    if (rm0) {
      const float* sp = s0p + p * KP;
      float4 x = *(const float4*)sp;
      float4 y = *(const float4*)(sp + 4);
      v[0]=x.x; v[1]=x.y; v[2]=x.z; v[3]=x.w;
      v[4]=y.x; v[5]=y.y; v[6]=y.z; v[7]=y.w;
      if (isDen0) {
        const float* pw = psh_s + cb0 + 16 * p;
        float t = 0.f;
        #pragma unroll
        for (int e2 = 0; e2 < 8; ++e2) t += v[e2] * v[e2] * pw[e2];
        gw1a += w0r * t;
      }
    } else {
      const float* sp = s0p + (size_t)p * KP * 160;
      #pragma unroll
      for (int e2 = 0; e2 < 8; ++e2) v[e2] = sp[(size_t)e2 * 160];
      if (isVT0) {
        const float* qw = qsh_s + cb0 + 16 * p;
        float t = 0.f;
        #pragma unroll
        for (int e2 = 0; e2 < 8; ++e2) t += v[e2] * v[e2] * qw[e2];
        gw2a += w0r * t;
      }
    }
  };
  auto load1 = [&](int p, float* v) {
    if (!act1) return;
    const float* sp = s1p + (size_t)p * KP * 160;
    #pragma unroll
    for (int e2 = 0; e2 < 8; ++e2) v[e2] = sp[(size_t)e2 * 160];
    const float* qw = qsh_s + cb1 + 16 * p;
    float t = 0.f;
    #pragma unroll
    for (int e2 = 0; e2 < 8; ++e2) t += v[e2] * v[e2] * qw[e2];
    gw2a += w1r * t;
  };
  auto wr = [&](const float* v0, const float* v1, __bf16* w0, __bf16* w1) {
    bf16x8 wv2;
    #pragma unroll
    for (int e2 = 0; e2 < 8; ++e2) wv2[e2] = (__bf16)v0[e2];
    *(bf16x8*)w0 = wv2;
    if (act1) {
      bf16x8 wv3;
      #pragma unroll
      for (int e2 = 0; e2 < 8; ++e2) wv3[e2] = (__bf16)v1[e2];
      *(bf16x8*)w1 = wv3;
    }
  };

  int ra = lane & 31, cc2 = lane >> 5;
  int t0 = wv;                 // 0..15, always < 25
  int ti0 = t0 / 5, tj0 = t0 - 5 * (t0 / 5);
  int rowa0 = ti0 * 32 + ra, rowb0 = tj0 * 32 + ra;
  int t1 = wv + 16;
  bool val1t = t1 < 25;
  int ti1 = t1 / 5, tj1 = t1 - 5 * (t1 / 5);
  int rowa1 = ti1 * 32 + ra, rowb1 = tj1 * 32 + ra;
  f32x16 acc10 = {}, acc20 = {}, acc11 = {}, acc21 = {};
  auto mf = [&](int BUF) {
    {
      bf16x8 a1 = *(const bf16x8*)&F.sDen[BUF][cc2][rowa0][0];
      bf16x8 b1 = *(const bf16x8*)&F.sGT[BUF][cc2][rowb0][0];
      bf16x8 a2 = *(const bf16x8*)&F.sG[BUF][cc2][rowa0][0];
      bf16x8 b2 = *(const bf16x8*)&F.sVT[BUF][cc2][rowb0][0];
      acc10 = __builtin_amdgcn_mfma_f32_32x32x16_bf16(a1, b1, acc10, 0, 0, 0);
      acc20 = __builtin_amdgcn_mfma_f32_32x32x16_bf16(a2, b2, acc20, 0, 0, 0);
    }
    if (val1t) {
      bf16x8 a1 = *(const bf16x8*)&F.sDen[BUF][cc2][rowa1][0];
      bf16x8 b1 = *(const bf16x8*)&F.sGT[BUF][cc2][rowb1][0];
      bf16x8 a2 = *(const bf16x8*)&F.sG[BUF][cc2][rowa1][0];
      bf16x8 b2 = *(const bf16x8*)&F.sVT[BUF][cc2][rowb1][0];
      acc11 = __builtin_amdgcn_mfma_f32_32x32x16_bf16(a1, b1, acc11, 0, 0, 0);
      acc21 = __builtin_amdgcn_mfma_f32_32x32x16_bf16(a2, b2, acc21, 0, 0, 0);
    }
  };

  load0(0, vA0); load1(0, vA1);
  load0(1, vB0); load1(1, vB1);
  wr(vA0, vA1, d00, d10);
  __syncthreads();
  for (int p = 0; p < NP; p += 2) {
    if (p + 2 < NP) { load0(p + 2, vA0); load1(p + 2, vA1); }
    mf(0);
    wr(vB0, vB1, d01, d11);
    wg_barrier();
    if (p + 3 < NP) { load0(p + 3, vB0); load1(p + 3, vB1); }
    mf(1);
    if (p + 2 < NP) wr(vA0, vA1, d00, d10);
    wg_barrier();
  }
  float g3 = 0.f;
  #pragma unroll
  for (int r2 = 0; r2 < 16; ++r2) g3 += acc10[r2] * acc20[r2];
  if (val1t) {
    #pragma unroll
    for (int r2 = 0; r2 < 16; ++r2) g3 += acc11[r2] * acc21[r2];
  }
  #pragma unroll
  for (int o = 32; o; o >>= 1) {
    g3 += __shfl_xor(g3, o);
    gw1a += __shfl_xor(gw1a, o);
    gw2a += __shfl_xor(gw2a, o);
  }
  if (lane == 0) { F.red[wv] = g3; F.red[16 + wv] = gw1a; F.red[32 + wv] = gw2a; }
  __syncthreads();
  if (tid == 0) {
    float s3 = 0.f, s1 = 0.f, s2 = 0.f;
    #pragma unroll
    for (int i = 0; i < 16; ++i) { s3 += F.red[i]; s1 += F.red[16 + i]; s2 += F.red[32 + i]; }
    float* o = sp1 + (size_t)b * 12;
    o[7] = s1; o[8] = s2; o[9] = s3;
  }
}

// ---- final reduction over batches ----
__global__ __launch_bounds__(512) void finalize_k(
    const float* __restrict__ sp1, float* __restrict__ out) {
  __shared__ float red[8][10];
  int tid = threadIdx.x;
  int wid = tid >> 6, lane = tid & 63;
  float v[10];
  const float* a = sp1 + (size_t)tid * 12;
  #pragma unroll
  for (int i = 0; i < 10; ++i) v[i] = a[i];
  #pragma unroll
  for (int i = 0; i < 10; ++i) {
    float s = v[i];
    #pragma unroll
    for (int o = 32; o; o >>= 1) s += __shfl_xor(s, o);
    v[i] = s;
  }
  if (lane == 0) {
    #pragma unroll
    for (int i = 0; i < 10; ++i) red[wid][i] = v[i];
  }
  __syncthreads();
  if (tid == 0) {
    float t[10];
    #pragma unroll
    for (int i = 0; i < 10; ++i) {
      float s = 0.f;
      #pragma unroll
      for (int w2 = 0; w2 < 8; ++w2) s += red[w2][i];
      t[i] = s;
    }
    float ce_s = t[0], ce_e = t[1], kls = t[2], kle = t[3];
    float w = t[4], spn = t[5], nans = t[6];
    float gw1 = t[7], gw2 = t[8], gw3 = t[9];
    float l_qa = (ce_s + ce_e) / (2.f * Bn);
    float l_fgw = (ALPHA * (gw1 + gw2 - 2.f * gw3) + (1.f - ALPHA) * w) / Bn;
    float l_span = (nans > 0.f) ? spn / fmaxf(nans, 1.f) : 0.f;
    float l_cons = 2.f * (kls + kle) / Bn;  // T^2 * ((kls+kle)/B) / 2 with T=2
    float total = l_qa + L_FGW * l_fgw + L_SPAN * l_span + L_CONS * l_cons;
    out[0] = total; out[1] = l_qa; out[2] = l_fgw; out[3] = l_span; out[4] = l_cons;
  }
}

extern "C" void kernel_launch(void* const* d_in, const int* in_sizes, int n_in,
                              void* d_out, int out_size, void* d_ws, size_t ws_size,
                              hipStream_t stream) {
  const float* en  = (const float*)d_in[0];
  const float* vi  = (const float*)d_in[1];
  const float* gam = (const float*)d_in[2];
  const float* Den = (const float*)d_in[3];
  const float* Dvi = (const float*)d_in[4];
  const float* M   = (const float*)d_in[5];
  const int* enst  = (const int*)d_in[6];
  const int* enen  = (const int*)d_in[7];
  const float* w_s = (const float*)d_in[8];
  const float* b_s = (const float*)d_in[9];
  const float* w_e = (const float*)d_in[10];
  const float* b_e = (const float*)d_in[11];
  float* sp1 = (float*)d_ws;               // 512*12 per-batch partials
  float* out = (float*)d_out;

  mega_k<<<Bn, 1024, 0, stream>>>(en, vi, w_s, b_s, w_e, b_e, gam, M, Den, Dvi,
                                  enst, enen, sp1);
  finalize_k<<<1, 512, 0, stream>>>(sp1, out);
}

// Round 20
// 111.752 us; speedup vs baseline: 1.1327x; 1.0566x over previous
//
#include <hip/hip_runtime.h>

#define Bn 512
#define Kn 160
#define Hn 256
#define ALPHA 0.5f
#define MAX_SPAN 30
#define L_FGW 0.1f
#define L_SPAN 0.5f
#define L_CONS 0.3f
#define KP 16
#define NP 10

typedef __bf16 bf16x8 __attribute__((ext_vector_type(8)));
typedef float f32x16 __attribute__((ext_vector_type(16)));
typedef float f32x4v __attribute__((ext_vector_type(4)));

// Phase A-D scratch and fgw scratch share one LDS union; p/q live OUTSIDE
// the union (E's gw1/gw2 fusion reads them during MFMA staging).
struct PhS {
  float prow[160][41];          // p row-partials (pad 41)
  float qcol[16][160];          // q partials per rm
  float vcol[16][160];          // vsc partials per rm
  float vscsh[160];
  float esh[160], eeh[160], vssh[160], veh[160];   // QA logits in-LDS
  float wsh[16];
  float bv[256];
  int bidx[256];
  int pspe[2];
};
struct FgS {
  __bf16 sDen[2][2][Kn][8];
  __bf16 sG[2][2][Kn][8];
  __bf16 sGT[2][2][Kn][8];
  __bf16 sVT[2][2][Kn][8];
  float red[48];
};

// raw barrier: LDS drained, global loads stay in flight (no vmcnt drain)
__device__ __forceinline__ void wg_barrier() {
  asm volatile("s_waitcnt lgkmcnt(0)" ::: "memory");
  __builtin_amdgcn_s_barrier();
  __builtin_amdgcn_sched_barrier(0);
}

// ---- one block per batch: fused gamma/M + QA streams -> E-loads issued ->
//      losses (latency hidden) -> fgw(+gw1/gw2 fused into staging) ----
__global__ __launch_bounds__(1024, 4) void mega_k(
    const float* __restrict__ en, const float* __restrict__ vi,
    const float* __restrict__ w_s, const float* __restrict__ b_s,
    const float* __restrict__ w_e, const float* __restrict__ b_e,
    const float* __restrict__ gam, const float* __restrict__ M,
    const float* __restrict__ Den, const float* __restrict__ Dvi,
    const int* __restrict__ enst, const int* __restrict__ enen,
    float* __restrict__ sp1) {
  __shared__ __align__(16) char shraw[sizeof(PhS)];
  __shared__ float psh_s[160];
  __shared__ float qsh_s[160];
  PhS& S = *(PhS*)shraw;
  FgS& F = *(FgS*)shraw;
  int b = blockIdx.x;
  int tid = threadIdx.x;
  int wv = tid >> 6, lane = tid & 63;
  const float* gam_b = gam + (size_t)b * 25600;
  const float* m_b   = M   + (size_t)b * 25600;
  const float* den_b = Den + (size_t)b * 25600;
  const float* dvi_b = Dvi + (size_t)b * 25600;
  int s0 = enst[b], e0 = enen[b];
  int s = min(max(s0, 0), Kn - 1);
  int e = max(s, min(max(e0, 0), Kn - 1));
  bool actA = tid < 640;
  int rm = tid / 40, c = tid - 40 * rm;    // A layout (uniform 16-row slabs)

  // ---- Phase A+C fused: gamma+M stats and QA logits in one 10-iter loop ----
  float4 ws4 = *(const float4*)(w_s + lane * 4);
  float4 we4 = *(const float4*)(w_e + lane * 4);
  float bs0 = b_s[0], be0 = b_e[0];
  const float* en_b = en + (size_t)b * 40960;
  const float* vi_b = vi + (size_t)b * 40960;
  float q4[4] = {0.f,0.f,0.f,0.f}, v4[4] = {0.f,0.f,0.f,0.f};
  float wloc = 0.f;
  #pragma unroll
  for (int it = 0; it < 10; ++it) {
    int crow = wv * 10 + it;     // C: one row per wave per iter
    f32x4v ev = __builtin_nontemporal_load((const f32x4v*)(en_b + (size_t)crow * 256 + lane * 4));
    f32x4v vv = __builtin_nontemporal_load((const f32x4v*)(vi_b + (size_t)crow * 256 + lane * 4));
    if (actA) {
      int r = 16 * it + rm;      // A: uniform 16-row slab
      float4 g = *(const float4*)(gam_b + (size_t)r * 160 + 4 * c);
      f32x4v m = __builtin_nontemporal_load((const f32x4v*)(m_b + (size_t)r * 160 + 4 * c));
      wloc += m[0]*g.x + m[1]*g.y + m[2]*g.z + m[3]*g.w;
      S.prow[r][c] = g.x + g.y + g.z + g.w;
      q4[0]+=g.x; q4[1]+=g.y; q4[2]+=g.z; q4[3]+=g.w;
      float f = (r >= s && r <= e) ? 1.f : 0.f;
      v4[0]+=f*g.x; v4[1]+=f*g.y; v4[2]+=f*g.z; v4[3]+=f*g.w;
    }
    float a0 = ev[0]*ws4.x + ev[1]*ws4.y + ev[2]*ws4.z + ev[3]*ws4.w;
    float a1 = ev[0]*we4.x + ev[1]*we4.y + ev[2]*we4.z + ev[3]*we4.w;
    float a2 = vv[0]*ws4.x + vv[1]*ws4.y + vv[2]*ws4.z + vv[3]*ws4.w;
    float a3 = vv[0]*we4.x + vv[1]*we4.y + vv[2]*we4.z + vv[3]*we4.w;
    #pragma unroll
    for (int o = 32; o; o >>= 1) {
      a0 += __shfl_xor(a0, o); a1 += __shfl_xor(a1, o);
      a2 += __shfl_xor(a2, o); a3 += __shfl_xor(a3, o);
    }
    if (lane == 0) {
      S.esh[crow] = a0 + bs0;  S.eeh[crow] = a1 + be0;
      S.vssh[crow] = a2 + bs0; S.veh[crow] = a3 + be0;
    }
  }
  if (actA) {
    #pragma unroll
    for (int j = 0; j < 4; ++j) { S.qcol[rm][4*c+j] = q4[j]; S.vcol[rm][4*c+j] = v4[j]; }
  }
  #pragma unroll
  for (int o = 32; o; o >>= 1) wloc += __shfl_xor(wloc, o);
  if (lane == 0) S.wsh[wv] = wloc;
  __syncthreads();
  if (tid < 160) {
    float sp = 0.f;
    #pragma unroll 8
    for (int c2 = 0; c2 < 40; ++c2) sp += S.prow[tid][c2];
    psh_s[tid] = sp;
    float sq = 0.f, sv = 0.f;
    #pragma unroll 4
    for (int k = 0; k < 16; ++k) { sq += S.qcol[k][tid]; sv += S.vcol[k][tid]; }
    qsh_s[tid] = sq;
    S.vscsh[tid] = sv;
  }
  __syncthreads();

  // ---- Phase E setup + panel-0/1 register loads issued EARLY (before D):
  //      D is serial compute with an idle memory pipe; E's cold-D load
  //      chains complete underneath it. wr (LDS) stays after D's barrier.
  bool rm0 = tid < 640;
  const float* s0p;
  __bf16 *d00, *d01;
  bool isDen0 = false, isVT0 = false;
  float w0r = 0.f;       // p[r] for D_en threads, q[j] for slot0-VT threads
  int cb0 = 0;           // 8*cc: column base within panel
  if (rm0) {
    int op = tid >= 320 ? 1 : 0;
    int fr = tid - 320 * op;
    int cc = fr >= 160 ? 1 : 0;
    int r = fr - 160 * cc;
    s0p = (op ? gam_b : den_b) + (size_t)r * 160 + 8 * cc;
    d00 = op ? &F.sG[0][cc][r][0] : &F.sDen[0][cc][r][0];
    d01 = op ? &F.sG[1][cc][r][0] : &F.sDen[1][cc][r][0];
    if (!op) { isDen0 = true; w0r = psh_s[r]; cb0 = 8 * cc; }
  } else {
    int f3 = tid - 640;
    int op = f3 >= 320 ? 1 : 0;
    int f4 = f3 - 320 * op;
    int cc = f4 >= 160 ? 1 : 0;
    int j = f4 - 160 * cc;
    s0p = (op ? dvi_b : gam_b) + (size_t)(8 * cc) * 160 + j;
    d00 = op ? &F.sVT[0][cc][j][0] : &F.sGT[0][cc][j][0];
    d01 = op ? &F.sVT[1][cc][j][0] : &F.sGT[1][cc][j][0];
    if (op) { isVT0 = true; w0r = qsh_s[j]; cb0 = 8 * cc; }
  }
  bool act1 = tid < 256;
  int f5 = tid + 64;
  int cc1 = f5 >= 160 ? 1 : 0;
  int j1 = f5 - 160 * cc1;
  const float* s1p = dvi_b + (size_t)(8 * cc1) * 160 + j1;
  __bf16* d10 = &F.sVT[0][cc1][j1][0];
  __bf16* d11 = &F.sVT[1][cc1][j1][0];
  float w1r = act1 ? qsh_s[j1] : 0.f;
  int cb1 = 8 * cc1;
  float gw1a = 0.f, gw2a = 0.f;

  float vA0[8], vA1[8], vB0[8], vB1[8];
  auto load0 = [&](int p, float* v) {
    if (rm0) {
      const float* sp = s0p + p * KP;
      float4 x = *(const float4*)sp;
      float4 y = *(const float4*)(sp + 4);
      v[0]=x.x; v[1]=x.y; v[2]=x.z; v[3]=x.w;
      v[4]=y.x; v[5]=y.y; v[6]=y.z; v[7]=y.w;
      if (isDen0) {
        const float* pw = psh_s + cb0 + 16 * p;
        float t = 0.f;
        #pragma unroll
        for (int e2 = 0; e2 < 8; ++e2) t += v[e2] * v[e2] * pw[e2];
        gw1a += w0r * t;
      }
    } else {
      const float* sp = s0p + (size_t)p * KP * 160;
      #pragma unroll
      for (int e2 = 0; e2 < 8; ++e2) v[e2] = sp[(size_t)e2 * 160];
      if (isVT0) {
        const float* qw = qsh_s + cb0 + 16 * p;
        float t = 0.f;
        #pragma unroll
        for (int e2 = 0; e2 < 8; ++e2) t += v[e2] * v[e2] * qw[e2];
        gw2a += w0r * t;
      }
    }
  };
  auto load1 = [&](int p, float* v) {
    if (!act1) return;
    const float* sp = s1p + (size_t)p * KP * 160;
    #pragma unroll
    for (int e2 = 0; e2 < 8; ++e2) v[e2] = sp[(size_t)e2 * 160];
    const float* qw = qsh_s + cb1 + 16 * p;
    float t = 0.f;
    #pragma unroll
    for (int e2 = 0; e2 < 8; ++e2) t += v[e2] * v[e2] * qw[e2];
    gw2a += w1r * t;
  };
  // issue panel 0/1 loads now — they drain while phase D runs
  load0(0, vA0); load1(0, vA1);
  load0(1, vB0); load1(1, vB1);

  // ---- Phase D: span argmax + QA CE + KL + span CE -> sp1[0..6] ----
  float best = -1e30f;
  int bfl = 0x7fffffff;
  if (tid < 160) {
    float vsi = S.vscsh[tid];
    int hi = min(tid + MAX_SPAN, Kn - 1);
    for (int ei = tid; ei <= hi; ++ei) {
      float v = vsi + S.vscsh[ei];
      if (v > best) { best = v; bfl = tid * Kn + ei; }  // first-max (np.argmax)
    }
  }
  if (tid < 256) { S.bv[tid] = best; S.bidx[tid] = bfl; }
  for (int st = 128; st > 0; st >>= 1) {
    __syncthreads();
    if (tid < st) {
      float v2 = S.bv[tid + st]; int i2 = S.bidx[tid + st];
      if (v2 > S.bv[tid] || (v2 == S.bv[tid] && i2 < S.bidx[tid])) { S.bv[tid] = v2; S.bidx[tid] = i2; }
    }
  }
  if (tid == 0) {
    int fl = S.bidx[0];
    int ps = fl / Kn, pe = fl - (fl / Kn) * Kn;
    if (s0 == 0 && e0 == 0) { ps = 0; pe = 0; }
    S.pspe[0] = ps; S.pspe[1] = pe;
    float sw = 0.f;
    #pragma unroll
    for (int i = 0; i < 16; ++i) sw += S.wsh[i];
    sp1[(size_t)b * 12 + 4] = sw;
  }
  __syncthreads();
  if (wv == 0) {
    float xes[3], xee[3], xvs[3], xve[3];
    #pragma unroll
    for (int j = 0; j < 3; ++j) {
      int idx = lane + 64 * j;
      bool val = idx < Kn;
      xes[j] = val ? S.esh[idx] : -1e30f;
      xee[j] = val ? S.eeh[idx] : -1e30f;
      xvs[j] = val ? S.vssh[idx] : -1e30f;
      xve[j] = val ? S.veh[idx] : -1e30f;
    }
    auto wlse = [&](float x0, float x1, float x2) -> float {
      float m = fmaxf(fmaxf(x0, x1), x2);
      #pragma unroll
      for (int o = 32; o; o >>= 1) m = fmaxf(m, __shfl_xor(m, o));
      float su = expf(x0 - m) + expf(x1 - m) + expf(x2 - m);
      #pragma unroll
      for (int o = 32; o; o >>= 1) su += __shfl_xor(su, o);
      return m + logf(su);
    };
    float l_es = wlse(xes[0], xes[1], xes[2]);
    float l_ee = wlse(xee[0], xee[1], xee[2]);
    float l_vs = wlse(xvs[0], xvs[1], xvs[2]);
    float l_ve = wlse(xve[0], xve[1], xve[2]);
    float lT_es = wlse(xes[0]*0.5f, xes[1]*0.5f, xes[2]*0.5f);
    float lT_ee = wlse(xee[0]*0.5f, xee[1]*0.5f, xee[2]*0.5f);
    float lT_vs = wlse(xvs[0]*0.5f, xvs[1]*0.5f, xvs[2]*0.5f);
    float lT_ve = wlse(xve[0]*0.5f, xve[1]*0.5f, xve[2]*0.5f);
    float kls = 0.f, kle = 0.f;
    #pragma unroll
    for (int j = 0; j < 3; ++j) {
      int idx = lane + 64 * j;
      if (idx < Kn) {
        float aa = xes[j]*0.5f - lT_es;
        float bb = xvs[j]*0.5f - lT_vs;
        kls += expf(aa) * (aa - bb);
        float cc = xee[j]*0.5f - lT_ee;
        float dd = xve[j]*0.5f - lT_ve;
        kle += expf(cc) * (cc - dd);
      }
    }
    #pragma unroll
    for (int o = 32; o; o >>= 1) { kls += __shfl_xor(kls, o); kle += __shfl_xor(kle, o); }
    if (lane == 0) {
      int sl = min(max(s0, 0), Kn - 1);
      int el = min(max(e0, 0), Kn - 1);
      float* o = sp1 + (size_t)b * 12;
      o[0] = l_es - S.esh[sl];
      o[1] = l_ee - S.eeh[el];
      o[2] = kls;
      o[3] = kle;
      bool answerable = (s0 > 0) || (e0 > 0);
      float ce = 0.5f * ((l_vs - S.vssh[S.pspe[0]]) + (l_ve - S.veh[S.pspe[1]]));
      o[5] = answerable ? ce : 0.f;
      o[6] = answerable ? 1.f : 0.f;
    }
  }
  __syncthreads();   // all Phase-D LDS reads done before fgw overwrites the union

  // ---- Phase E: fgw gw3 via MFMA; gw1/gw2 fused into the staging loads ----
  auto wr = [&](const float* v0, const float* v1, __bf16* w0, __bf16* w1) {
    bf16x8 wv2;
    #pragma unroll
    for (int e2 = 0; e2 < 8; ++e2) wv2[e2] = (__bf16)v0[e2];
    *(bf16x8*)w0 = wv2;
    if (act1) {
      bf16x8 wv3;
      #pragma unroll
      for (int e2 = 0; e2 < 8; ++e2) wv3[e2] = (__bf16)v1[e2];
      *(bf16x8*)w1 = wv3;
    }
  };

  int ra = lane & 31, cc2 = lane >> 5;
  int t0 = wv;                 // 0..15, always < 25
  int ti0 = t0 / 5, tj0 = t0 - 5 * (t0 / 5);
  int rowa0 = ti0 * 32 + ra, rowb0 = tj0 * 32 + ra;
  int t1 = wv + 16;
  bool val1t = t1 < 25;
  int ti1 = t1 / 5, tj1 = t1 - 5 * (t1 / 5);
  int rowa1 = ti1 * 32 + ra, rowb1 = tj1 * 32 + ra;
  f32x16 acc10 = {}, acc20 = {}, acc11 = {}, acc21 = {};
  auto mf = [&](int BUF) {
    {
      bf16x8 a1 = *(const bf16x8*)&F.sDen[BUF][cc2][rowa0][0];
      bf16x8 b1 = *(const bf16x8*)&F.sGT[BUF][cc2][rowb0][0];
      bf16x8 a2 = *(const bf16x8*)&F.sG[BUF][cc2][rowa0][0];
      bf16x8 b2 = *(const bf16x8*)&F.sVT[BUF][cc2][rowb0][0];
      acc10 = __builtin_amdgcn_mfma_f32_32x32x16_bf16(a1, b1, acc10, 0, 0, 0);
      acc20 = __builtin_amdgcn_mfma_f32_32x32x16_bf16(a2, b2, acc20, 0, 0, 0);
    }
    if (val1t) {
      bf16x8 a1 = *(const bf16x8*)&F.sDen[BUF][cc2][rowa1][0];
      bf16x8 b1 = *(const bf16x8*)&F.sGT[BUF][cc2][rowb1][0];
      bf16x8 a2 = *(const bf16x8*)&F.sG[BUF][cc2][rowa1][0];
      bf16x8 b2 = *(const bf16x8*)&F.sVT[BUF][cc2][rowb1][0];
      acc11 = __builtin_amdgcn_mfma_f32_32x32x16_bf16(a1, b1, acc11, 0, 0, 0);
      acc21 = __builtin_amdgcn_mfma_f32_32x32x16_bf16(a2, b2, acc21, 0, 0, 0);
    }
  };

  wr(vA0, vA1, d00, d10);
  __syncthreads();
  for (int p = 0; p < NP; p += 2) {
    if (p + 2 < NP) { load0(p + 2, vA0); load1(p + 2, vA1); }
    mf(0);
    wr(vB0, vB1, d01, d11);
    wg_barrier();
    if (p + 3 < NP) { load0(p + 3, vB0); load1(p + 3, vB1); }
    mf(1);
    if (p + 2 < NP) wr(vA0, vA1, d00, d10);
    wg_barrier();
  }
  float g3 = 0.f;
  #pragma unroll
  for (int r2 = 0; r2 < 16; ++r2) g3 += acc10[r2] * acc20[r2];
  if (val1t) {
    #pragma unroll
    for (int r2 = 0; r2 < 16; ++r2) g3 += acc11[r2] * acc21[r2];
  }
  #pragma unroll
  for (int o = 32; o; o >>= 1) {
    g3 += __shfl_xor(g3, o);
    gw1a += __shfl_xor(gw1a, o);
    gw2a += __shfl_xor(gw2a, o);
  }
  if (lane == 0) { F.red[wv] = g3; F.red[16 + wv] = gw1a; F.red[32 + wv] = gw2a; }
  __syncthreads();
  if (tid == 0) {
    float s3 = 0.f, s1 = 0.f, s2 = 0.f;
    #pragma unroll
    for (int i = 0; i < 16; ++i) { s3 += F.red[i]; s1 += F.red[16 + i]; s2 += F.red[32 + i]; }
    float* o = sp1 + (size_t)b * 12;
    o[7] = s1; o[8] = s2; o[9] = s3;
  }
}

// ---- final reduction over batches ----
__global__ __launch_bounds__(512) void finalize_k(
    const float* __restrict__ sp1, float* __restrict__ out) {
  __shared__ float red[8][10];
  int tid = threadIdx.x;
  int wid = tid >> 6, lane = tid & 63;
  float v[10];
  const float* a = sp1 + (size_t)tid * 12;
  #pragma unroll
  for (int i = 0; i < 10; ++i) v[i] = a[i];
  #pragma unroll
  for (int i = 0; i < 10; ++i) {
    float s = v[i];
    #pragma unroll
    for (int o = 32; o; o >>= 1) s += __shfl_xor(s, o);
    v[i] = s;
  }
  if (lane == 0) {
    #pragma unroll
    for (int i = 0; i < 10; ++i) red[wid][i] = v[i];
  }
  __syncthreads();
  if (tid == 0) {
    float t[10];
    #pragma unroll
    for (int i = 0; i < 10; ++i) {
      float s = 0.f;
      #pragma unroll
      for (int w2 = 0; w2 < 8; ++w2) s += red[w2][i];
      t[i] = s;
    }
    float ce_s = t[0], ce_e = t[1], kls = t[2], kle = t[3];
    float w = t[4], spn = t[5], nans = t[6];
    float gw1 = t[7], gw2 = t[8], gw3 = t[9];
    float l_qa = (ce_s + ce_e) / (2.f * Bn);
    float l_fgw = (ALPHA * (gw1 + gw2 - 2.f * gw3) + (1.f - ALPHA) * w) / Bn;
    float l_span = (nans > 0.f) ? spn / fmaxf(nans, 1.f) : 0.f;
    float l_cons = 2.f * (kls + kle) / Bn;  // T^2 * ((kls+kle)/B) / 2 with T=2
    float total = l_qa + L_FGW * l_fgw + L_SPAN * l_span + L_CONS * l_cons;
    out[0] = total; out[1] = l_qa; out[2] = l_fgw; out[3] = l_span; out[4] = l_cons;
  }
}

extern "C" void kernel_launch(void* const* d_in, const int* in_sizes, int n_in,
                              void* d_out, int out_size, void* d_ws, size_t ws_size,
                              hipStream_t stream) {
  const float* en  = (const float*)d_in[0];
  const float* vi  = (const float*)d_in[1];
  const float* gam = (const float*)d_in[2];
  const float* Den = (const float*)d_in[3];
  const float* Dvi = (const float*)d_in[4];
  const float* M   = (const float*)d_in[5];
  const int* enst  = (const int*)d_in[6];
  const int* enen  = (const int*)d_in[7];
  const float* w_s = (const float*)d_in[8];
  const float* b_s = (const float*)d_in[9];
  const float* w_e = (const float*)d_in[10];
  const float* b_e = (const float*)d_in[11];
  float* sp1 = (float*)d_ws;               // 512*12 per-batch partials
  float* out = (float*)d_out;

  mega_k<<<Bn, 1024, 0, stream>>>(en, vi, w_s, b_s, w_e, b_e, gam, M, Den, Dvi,
                                  enst, enen, sp1);
  finalize_k<<<1, 512, 0, stream>>>(sp1, out);
}

// Round 21
// 109.879 us; speedup vs baseline: 1.1520x; 1.0170x over previous
//
#include <hip/hip_runtime.h>

#define Bn 512
#define Kn 160
#define Hn 256
#define ALPHA 0.5f
#define MAX_SPAN 30
#define L_FGW 0.1f
#define L_SPAN 0.5f
#define L_CONS 0.3f
#define KP 16
#define NP 10

typedef __bf16 bf16x8 __attribute__((ext_vector_type(8)));
typedef float f32x16 __attribute__((ext_vector_type(16)));
typedef float f32x4v __attribute__((ext_vector_type(4)));

// Phase A-D scratch and fgw scratch share one LDS union; p/q live OUTSIDE
// the union (E's gw1/gw2 fusion reads them during MFMA staging).
struct PhS {
  float prow[160][41];          // p row-partials (pad 41)
  float qcol[16][160];          // q partials per rm
  float vcol[16][160];          // vsc partials per rm
  float vscsh[160];
  float esh[160], eeh[160], vssh[160], veh[160];   // QA logits in-LDS
  float wsh[16];
  float bv[256];
  int bidx[256];
  int pspe[2];
};
struct FgS {
  __bf16 sDen[2][2][Kn][8];
  __bf16 sG[2][2][Kn][8];
  __bf16 sGT[2][2][Kn][8];
  __bf16 sVT[2][2][Kn][8];
  float red[48];
};

// raw barrier: LDS drained, global loads stay in flight (no vmcnt drain)
__device__ __forceinline__ void wg_barrier() {
  asm volatile("s_waitcnt lgkmcnt(0)" ::: "memory");
  __builtin_amdgcn_s_barrier();
  __builtin_amdgcn_sched_barrier(0);
}

// ---- one block per batch: fused gamma/M + QA streams -> losses -> fgw(+gw1/gw2) ----
__global__ __launch_bounds__(1024, 4) void mega_k(
    const float* __restrict__ en, const float* __restrict__ vi,
    const float* __restrict__ w_s, const float* __restrict__ b_s,
    const float* __restrict__ w_e, const float* __restrict__ b_e,
    const float* __restrict__ gam, const float* __restrict__ M,
    const float* __restrict__ Den, const float* __restrict__ Dvi,
    const int* __restrict__ enst, const int* __restrict__ enen,
    float* __restrict__ sp1) {
  __shared__ __align__(16) char shraw[sizeof(PhS)];
  __shared__ float psh_s[160];
  __shared__ float qsh_s[160];
  PhS& S = *(PhS*)shraw;
  FgS& F = *(FgS*)shraw;
  int b = blockIdx.x;
  int tid = threadIdx.x;
  int wv = tid >> 6, lane = tid & 63;
  const float* gam_b = gam + (size_t)b * 25600;
  const float* m_b   = M   + (size_t)b * 25600;
  const float* den_b = Den + (size_t)b * 25600;
  const float* dvi_b = Dvi + (size_t)b * 25600;
  int s0 = enst[b], e0 = enen[b];
  int s = min(max(s0, 0), Kn - 1);
  int e = max(s, min(max(e0, 0), Kn - 1));
  bool actA = tid < 640;
  int rm = tid / 40, c = tid - 40 * rm;    // A layout (uniform 16-row slabs)

  // ---- Phase A+C fused: gamma+M stats and QA logits in one 10-iter loop ----
  float4 ws4 = *(const float4*)(w_s + lane * 4);
  float4 we4 = *(const float4*)(w_e + lane * 4);
  float bs0 = b_s[0], be0 = b_e[0];
  const float* en_b = en + (size_t)b * 40960;
  const float* vi_b = vi + (size_t)b * 40960;
  float q4[4] = {0.f,0.f,0.f,0.f}, v4[4] = {0.f,0.f,0.f,0.f};
  float wloc = 0.f;
  #pragma unroll
  for (int it = 0; it < 10; ++it) {
    int crow = wv * 10 + it;     // C: one row per wave per iter
    f32x4v ev = __builtin_nontemporal_load((const f32x4v*)(en_b + (size_t)crow * 256 + lane * 4));
    f32x4v vv = __builtin_nontemporal_load((const f32x4v*)(vi_b + (size_t)crow * 256 + lane * 4));
    if (actA) {
      int r = 16 * it + rm;      // A: uniform 16-row slab
      float4 g = *(const float4*)(gam_b + (size_t)r * 160 + 4 * c);
      f32x4v m = __builtin_nontemporal_load((const f32x4v*)(m_b + (size_t)r * 160 + 4 * c));
      wloc += m[0]*g.x + m[1]*g.y + m[2]*g.z + m[3]*g.w;
      S.prow[r][c] = g.x + g.y + g.z + g.w;
      q4[0]+=g.x; q4[1]+=g.y; q4[2]+=g.z; q4[3]+=g.w;
      float f = (r >= s && r <= e) ? 1.f : 0.f;
      v4[0]+=f*g.x; v4[1]+=f*g.y; v4[2]+=f*g.z; v4[3]+=f*g.w;
    }
    float a0 = ev[0]*ws4.x + ev[1]*ws4.y + ev[2]*ws4.z + ev[3]*ws4.w;
    float a1 = ev[0]*we4.x + ev[1]*we4.y + ev[2]*we4.z + ev[3]*we4.w;
    float a2 = vv[0]*ws4.x + vv[1]*ws4.y + vv[2]*ws4.z + vv[3]*ws4.w;
    float a3 = vv[0]*we4.x + vv[1]*we4.y + vv[2]*we4.z + vv[3]*we4.w;
    #pragma unroll
    for (int o = 32; o; o >>= 1) {
      a0 += __shfl_xor(a0, o); a1 += __shfl_xor(a1, o);
      a2 += __shfl_xor(a2, o); a3 += __shfl_xor(a3, o);
    }
    if (lane == 0) {
      S.esh[crow] = a0 + bs0;  S.eeh[crow] = a1 + be0;
      S.vssh[crow] = a2 + bs0; S.veh[crow] = a3 + be0;
    }
  }
  if (actA) {
    #pragma unroll
    for (int j = 0; j < 4; ++j) { S.qcol[rm][4*c+j] = q4[j]; S.vcol[rm][4*c+j] = v4[j]; }
  }
  #pragma unroll
  for (int o = 32; o; o >>= 1) wloc += __shfl_xor(wloc, o);
  if (lane == 0) S.wsh[wv] = wloc;
  __syncthreads();
  if (tid < 160) {
    float sp = 0.f;
    #pragma unroll 8
    for (int c2 = 0; c2 < 40; ++c2) sp += S.prow[tid][c2];
    psh_s[tid] = sp;
    float sq = 0.f, sv = 0.f;
    #pragma unroll 4
    for (int k = 0; k < 16; ++k) { sq += S.qcol[k][tid]; sv += S.vcol[k][tid]; }
    qsh_s[tid] = sq;
    S.vscsh[tid] = sv;
  }
  __syncthreads();

  // ---- Phase D: span argmax + QA CE + KL + span CE -> sp1[0..6] ----
  float best = -1e30f;
  int bfl = 0x7fffffff;
  if (tid < 160) {
    float vsi = S.vscsh[tid];
    int hi = min(tid + MAX_SPAN, Kn - 1);
    for (int ei = tid; ei <= hi; ++ei) {
      float v = vsi + S.vscsh[ei];
      if (v > best) { best = v; bfl = tid * Kn + ei; }  // first-max (np.argmax)
    }
  }
  if (tid < 256) { S.bv[tid] = best; S.bidx[tid] = bfl; }
  for (int st = 128; st > 0; st >>= 1) {
    __syncthreads();
    if (tid < st) {
      float v2 = S.bv[tid + st]; int i2 = S.bidx[tid + st];
      if (v2 > S.bv[tid] || (v2 == S.bv[tid] && i2 < S.bidx[tid])) { S.bv[tid] = v2; S.bidx[tid] = i2; }
    }
  }
  if (tid == 0) {
    int fl = S.bidx[0];
    int ps = fl / Kn, pe = fl - (fl / Kn) * Kn;
    if (s0 == 0 && e0 == 0) { ps = 0; pe = 0; }
    S.pspe[0] = ps; S.pspe[1] = pe;
    float sw = 0.f;
    #pragma unroll
    for (int i = 0; i < 16; ++i) sw += S.wsh[i];
    sp1[(size_t)b * 12 + 4] = sw;
  }
  __syncthreads();
  if (wv == 0) {
    float xes[3], xee[3], xvs[3], xve[3];
    #pragma unroll
    for (int j = 0; j < 3; ++j) {
      int idx = lane + 64 * j;
      bool val = idx < Kn;
      xes[j] = val ? S.esh[idx] : -1e30f;
      xee[j] = val ? S.eeh[idx] : -1e30f;
      xvs[j] = val ? S.vssh[idx] : -1e30f;
      xve[j] = val ? S.veh[idx] : -1e30f;
    }
    auto wlse = [&](float x0, float x1, float x2) -> float {
      float m = fmaxf(fmaxf(x0, x1), x2);
      #pragma unroll
      for (int o = 32; o; o >>= 1) m = fmaxf(m, __shfl_xor(m, o));
      float su = expf(x0 - m) + expf(x1 - m) + expf(x2 - m);
      #pragma unroll
      for (int o = 32; o; o >>= 1) su += __shfl_xor(su, o);
      return m + logf(su);
    };
    float l_es = wlse(xes[0], xes[1], xes[2]);
    float l_ee = wlse(xee[0], xee[1], xee[2]);
    float l_vs = wlse(xvs[0], xvs[1], xvs[2]);
    float l_ve = wlse(xve[0], xve[1], xve[2]);
    float lT_es = wlse(xes[0]*0.5f, xes[1]*0.5f, xes[2]*0.5f);
    float lT_ee = wlse(xee[0]*0.5f, xee[1]*0.5f, xee[2]*0.5f);
    float lT_vs = wlse(xvs[0]*0.5f, xvs[1]*0.5f, xvs[2]*0.5f);
    float lT_ve = wlse(xve[0]*0.5f, xve[1]*0.5f, xve[2]*0.5f);
    float kls = 0.f, kle = 0.f;
    #pragma unroll
    for (int j = 0; j < 3; ++j) {
      int idx = lane + 64 * j;
      if (idx < Kn) {
        float aa = xes[j]*0.5f - lT_es;
        float bb = xvs[j]*0.5f - lT_vs;
        kls += expf(aa) * (aa - bb);
        float cc = xee[j]*0.5f - lT_ee;
        float dd = xve[j]*0.5f - lT_ve;
        kle += expf(cc) * (cc - dd);
      }
    }
    #pragma unroll
    for (int o = 32; o; o >>= 1) { kls += __shfl_xor(kls, o); kle += __shfl_xor(kle, o); }
    if (lane == 0) {
      int sl = min(max(s0, 0), Kn - 1);
      int el = min(max(e0, 0), Kn - 1);
      float* o = sp1 + (size_t)b * 12;
      o[0] = l_es - S.esh[sl];
      o[1] = l_ee - S.eeh[el];
      o[2] = kls;
      o[3] = kle;
      bool answerable = (s0 > 0) || (e0 > 0);
      float ce = 0.5f * ((l_vs - S.vssh[S.pspe[0]]) + (l_ve - S.veh[S.pspe[1]]));
      o[5] = answerable ? ce : 0.f;
      o[6] = answerable ? 1.f : 0.f;
    }
  }
  __syncthreads();   // all Phase-D LDS reads done before fgw overwrites the union

  // ---- Phase E: fgw gw3 via MFMA; gw1/gw2 fused into the staging loads
  // (each D_en/D_vi element passes through exactly once, fp32, pre-bf16).
  bool rm0 = tid < 640;
  const float* s0p;
  __bf16 *d00, *d01;
  bool isDen0 = false, isVT0 = false;
  float w0r = 0.f;       // p[r] for D_en threads, q[j] for slot0-VT threads
  int cb0 = 0;           // 8*cc: column base within panel
  if (rm0) {
    int op = tid >= 320 ? 1 : 0;
    int fr = tid - 320 * op;
    int cc = fr >= 160 ? 1 : 0;
    int r = fr - 160 * cc;
    s0p = (op ? gam_b : den_b) + (size_t)r * 160 + 8 * cc;
    d00 = op ? &F.sG[0][cc][r][0] : &F.sDen[0][cc][r][0];
    d01 = op ? &F.sG[1][cc][r][0] : &F.sDen[1][cc][r][0];
    if (!op) { isDen0 = true; w0r = psh_s[r]; cb0 = 8 * cc; }
  } else {
    int f3 = tid - 640;
    int op = f3 >= 320 ? 1 : 0;
    int f4 = f3 - 320 * op;
    int cc = f4 >= 160 ? 1 : 0;
    int j = f4 - 160 * cc;
    s0p = (op ? dvi_b : gam_b) + (size_t)(8 * cc) * 160 + j;
    d00 = op ? &F.sVT[0][cc][j][0] : &F.sGT[0][cc][j][0];
    d01 = op ? &F.sVT[1][cc][j][0] : &F.sGT[1][cc][j][0];
    if (op) { isVT0 = true; w0r = qsh_s[j]; cb0 = 8 * cc; }
  }
  bool act1 = tid < 256;
  int f5 = tid + 64;
  int cc1 = f5 >= 160 ? 1 : 0;
  int j1 = f5 - 160 * cc1;
  const float* s1p = dvi_b + (size_t)(8 * cc1) * 160 + j1;
  __bf16* d10 = &F.sVT[0][cc1][j1][0];
  __bf16* d11 = &F.sVT[1][cc1][j1][0];
  float w1r = act1 ? qsh_s[j1] : 0.f;
  int cb1 = 8 * cc1;
  float gw1a = 0.f, gw2a = 0.f;

  float vA0[8], vA1[8], vB0[8], vB1[8];
  auto load0 = [&](int p, float* v) {
    if (rm0) {
      const float* sp = s0p + p * KP;
      float4 x = *(const float4*)sp;
      float4 y = *(const float4*)(sp + 4);
      v[0]=x.x; v[1]=x.y; v[2]=x.z; v[3]=x.w;
      v[4]=y.x; v[5]=y.y; v[6]=y.z; v[7]=y.w;
      if (isDen0) {
        const float* pw = psh_s + cb0 + 16 * p;
        float t = 0.f;
        #pragma unroll
        for (int e2 = 0; e2 < 8; ++e2) t += v[e2] * v[e2] * pw[e2];
        gw1a += w0r * t;
      }
    } else {
      const float* sp = s0p + (size_t)p * KP * 160;
      #pragma unroll
      for (int e2 = 0; e2 < 8; ++e2) v[e2] = sp[(size_t)e2 * 160];
      if (isVT0) {
        const float* qw = qsh_s + cb0 + 16 * p;
        float t = 0.f;
        #pragma unroll
        for (int e2 = 0; e2 < 8; ++e2) t += v[e2] * v[e2] * qw[e2];
        gw2a += w0r * t;
      }
    }
  };
  auto load1 = [&](int p, float* v) {
    if (!act1) return;
    const float* sp = s1p + (size_t)p * KP * 160;
    #pragma unroll
    for (int e2 = 0; e2 < 8; ++e2) v[e2] = sp[(size_t)e2 * 160];
    const float* qw = qsh_s + cb1 + 16 * p;
    float t = 0.f;
    #pragma unroll
    for (int e2 = 0; e2 < 8; ++e2) t += v[e2] * v[e2] * qw[e2];
    gw2a += w1r * t;
  };
  auto wr = [&](const float* v0, const float* v1, __bf16* w0, __bf16* w1) {
    bf16x8 wv2;
    #pragma unroll
    for (int e2 = 0; e2 < 8; ++e2) wv2[e2] = (__bf16)v0[e2];
    *(bf16x8*)w0 = wv2;
    if (act1) {
      bf16x8 wv3;
      #pragma unroll
      for (int e2 = 0; e2 < 8; ++e2) wv3[e2] = (__bf16)v1[e2];
      *(bf16x8*)w1 = wv3;
    }
  };

  int ra = lane & 31, cc2 = lane >> 5;
  int t0 = wv;                 // 0..15, always < 25
  int ti0 = t0 / 5, tj0 = t0 - 5 * (t0 / 5);
  int rowa0 = ti0 * 32 + ra, rowb0 = tj0 * 32 + ra;
  int t1 = wv + 16;
  bool val1t = t1 < 25;
  int ti1 = t1 / 5, tj1 = t1 - 5 * (t1 / 5);
  int rowa1 = ti1 * 32 + ra, rowb1 = tj1 * 32 + ra;
  f32x16 acc10 = {}, acc20 = {}, acc11 = {}, acc21 = {};
  auto mf = [&](int BUF) {
    __builtin_amdgcn_s_setprio(1);   // favor MFMA waves vs co-resident block's streams
    {
      bf16x8 a1 = *(const bf16x8*)&F.sDen[BUF][cc2][rowa0][0];
      bf16x8 b1 = *(const bf16x8*)&F.sGT[BUF][cc2][rowb0][0];
      bf16x8 a2 = *(const bf16x8*)&F.sG[BUF][cc2][rowa0][0];
      bf16x8 b2 = *(const bf16x8*)&F.sVT[BUF][cc2][rowb0][0];
      acc10 = __builtin_amdgcn_mfma_f32_32x32x16_bf16(a1, b1, acc10, 0, 0, 0);
      acc20 = __builtin_amdgcn_mfma_f32_32x32x16_bf16(a2, b2, acc20, 0, 0, 0);
    }
    if (val1t) {
      bf16x8 a1 = *(const bf16x8*)&F.sDen[BUF][cc2][rowa1][0];
      bf16x8 b1 = *(const bf16x8*)&F.sGT[BUF][cc2][rowb1][0];
      bf16x8 a2 = *(const bf16x8*)&F.sG[BUF][cc2][rowa1][0];
      bf16x8 b2 = *(const bf16x8*)&F.sVT[BUF][cc2][rowb1][0];
      acc11 = __builtin_amdgcn_mfma_f32_32x32x16_bf16(a1, b1, acc11, 0, 0, 0);
      acc21 = __builtin_amdgcn_mfma_f32_32x32x16_bf16(a2, b2, acc21, 0, 0, 0);
    }
    __builtin_amdgcn_s_setprio(0);
  };

  load0(0, vA0); load1(0, vA1);
  load0(1, vB0); load1(1, vB1);
  wr(vA0, vA1, d00, d10);
  __syncthreads();
  for (int p = 0; p < NP; p += 2) {
    if (p + 2 < NP) { load0(p + 2, vA0); load1(p + 2, vA1); }
    mf(0);
    wr(vB0, vB1, d01, d11);
    wg_barrier();
    if (p + 3 < NP) { load0(p + 3, vB0); load1(p + 3, vB1); }
    mf(1);
    if (p + 2 < NP) wr(vA0, vA1, d00, d10);
    wg_barrier();
  }
  float g3 = 0.f;
  #pragma unroll
  for (int r2 = 0; r2 < 16; ++r2) g3 += acc10[r2] * acc20[r2];
  if (val1t) {
    #pragma unroll
    for (int r2 = 0; r2 < 16; ++r2) g3 += acc11[r2] * acc21[r2];
  }
  #pragma unroll
  for (int o = 32; o; o >>= 1) {
    g3 += __shfl_xor(g3, o);
    gw1a += __shfl_xor(gw1a, o);
    gw2a += __shfl_xor(gw2a, o);
  }
  if (lane == 0) { F.red[wv] = g3; F.red[16 + wv] = gw1a; F.red[32 + wv] = gw2a; }
  __syncthreads();
  if (tid == 0) {
    float s3 = 0.f, s1 = 0.f, s2 = 0.f;
    #pragma unroll
    for (int i = 0; i < 16; ++i) { s3 += F.red[i]; s1 += F.red[16 + i]; s2 += F.red[32 + i]; }
    float* o = sp1 + (size_t)b * 12;
    o[7] = s1; o[8] = s2; o[9] = s3;
  }
}

// ---- final reduction over batches ----
__global__ __launch_bounds__(512) void finalize_k(
    const float* __restrict__ sp1, float* __restrict__ out) {
  __shared__ float red[8][10];
  int tid = threadIdx.x;
  int wid = tid >> 6, lane = tid & 63;
  float v[10];
  const float* a = sp1 + (size_t)tid * 12;
  #pragma unroll
  for (int i = 0; i < 10; ++i) v[i] = a[i];
  #pragma unroll
  for (int i = 0; i < 10; ++i) {
    float s = v[i];
    #pragma unroll
    for (int o = 32; o; o >>= 1) s += __shfl_xor(s, o);
    v[i] = s;
  }
  if (lane == 0) {
    #pragma unroll
    for (int i = 0; i < 10; ++i) red[wid][i] = v[i];
  }
  __syncthreads();
  if (tid == 0) {
    float t[10];
    #pragma unroll
    for (int i = 0; i < 10; ++i) {
      float s = 0.f;
      #pragma unroll
      for (int w2 = 0; w2 < 8; ++w2) s += red[w2][i];
      t[i] = s;
    }
    float ce_s = t[0], ce_e = t[1], kls = t[2], kle = t[3];
    float w = t[4], spn = t[5], nans = t[6];
    float gw1 = t[7], gw2 = t[8], gw3 = t[9];
    float l_qa = (ce_s + ce_e) / (2.f * Bn);
    float l_fgw = (ALPHA * (gw1 + gw2 - 2.f * gw3) + (1.f - ALPHA) * w) / Bn;
    float l_span = (nans > 0.f) ? spn / fmaxf(nans, 1.f) : 0.f;
    float l_cons = 2.f * (kls + kle) / Bn;  // T^2 * ((kls+kle)/B) / 2 with T=2
    float total = l_qa + L_FGW * l_fgw + L_SPAN * l_span + L_CONS * l_cons;
    out[0] = total; out[1] = l_qa; out[2] = l_fgw; out[3] = l_span; out[4] = l_cons;
  }
}

extern "C" void kernel_launch(void* const* d_in, const int* in_sizes, int n_in,
                              void* d_out, int out_size, void* d_ws, size_t ws_size,
                              hipStream_t stream) {
  const float* en  = (const float*)d_in[0];
  const float* vi  = (const float*)d_in[1];
  const float* gam = (const float*)d_in[2];
  const float* Den = (const float*)d_in[3];
  const float* Dvi = (const float*)d_in[4];
  const float* M   = (const float*)d_in[5];
  const int* enst  = (const int*)d_in[6];
  const int* enen  = (const int*)d_in[7];
  const float* w_s = (const float*)d_in[8];
  const float* b_s = (const float*)d_in[9];
  const float* w_e = (const float*)d_in[10];
  const float* b_e = (const float*)d_in[11];
  float* sp1 = (float*)d_ws;               // 512*12 per-batch partials
  float* out = (float*)d_out;

  mega_k<<<Bn, 1024, 0, stream>>>(en, vi, w_s, b_s, w_e, b_e, gam, M, Den, Dvi,
                                  enst, enen, sp1);
  finalize_k<<<1, 512, 0, stream>>>(sp1, out);
}

// Round 22
// 108.943 us; speedup vs baseline: 1.1619x; 1.0086x over previous
//
#include <hip/hip_runtime.h>

#define Bn 512
#define Kn 160
#define Hn 256
#define ALPHA 0.5f
#define MAX_SPAN 30
#define L_FGW 0.1f
#define L_SPAN 0.5f
#define L_CONS 0.3f
#define KP 16
#define NP 10

typedef __bf16 bf16x8 __attribute__((ext_vector_type(8)));
typedef float f32x16 __attribute__((ext_vector_type(16)));
typedef float f32x4v __attribute__((ext_vector_type(4)));

// Phase A-D scratch and fgw scratch share one LDS union; p/q live OUTSIDE
// the union (E's gw1/gw2 fusion reads them during MFMA staging).
struct PhS {
  float prow[160][41];          // p row-partials (pad 41)
  float qcol[16][160];          // q partials per rm
  float vcol[16][160];          // vsc partials per rm
  float vscsh[160];
  float esh[160], eeh[160], vssh[160], veh[160];   // QA logits in-LDS
  float wsh[16];
  float bv[256];
  int bidx[256];
  int pspe[2];
};
struct FgS {
  __bf16 sDen[2][2][Kn][8];
  __bf16 sG[2][2][Kn][8];
  __bf16 sGT[2][2][Kn][8];
  __bf16 sVT[2][2][Kn][8];
  float red[48];
};

// raw barrier: LDS drained, global loads stay in flight (no vmcnt drain)
__device__ __forceinline__ void wg_barrier() {
  asm volatile("s_waitcnt lgkmcnt(0)" ::: "memory");
  __builtin_amdgcn_s_barrier();
  __builtin_amdgcn_sched_barrier(0);
}

// ---- one block per batch: fused gamma/M + QA streams -> losses -> fgw(+gw1/gw2) ----
__global__ __launch_bounds__(1024, 4) void mega_k(
    const float* __restrict__ en, const float* __restrict__ vi,
    const float* __restrict__ w_s, const float* __restrict__ b_s,
    const float* __restrict__ w_e, const float* __restrict__ b_e,
    const float* __restrict__ gam, const float* __restrict__ M,
    const float* __restrict__ Den, const float* __restrict__ Dvi,
    const int* __restrict__ enst, const int* __restrict__ enen,
    float* __restrict__ sp1) {
  __shared__ __align__(16) char shraw[sizeof(PhS)];
  __shared__ float psh_s[160];
  __shared__ float qsh_s[160];
  PhS& S = *(PhS*)shraw;
  FgS& F = *(FgS*)shraw;
  int b = blockIdx.x;
  int tid = threadIdx.x;
  int wv = tid >> 6, lane = tid & 63;
  const float* gam_b = gam + (size_t)b * 25600;
  const float* m_b   = M   + (size_t)b * 25600;
  const float* den_b = Den + (size_t)b * 25600;
  const float* dvi_b = Dvi + (size_t)b * 25600;
  int s0 = enst[b], e0 = enen[b];
  int s = min(max(s0, 0), Kn - 1);
  int e = max(s, min(max(e0, 0), Kn - 1));
  bool actA = tid < 640;
  int rm = tid / 40, c = tid - 40 * rm;    // A layout (uniform 16-row slabs)

  // ---- Phase A+C fused: gamma+M stats and QA logits in one 10-iter loop ----
  float4 ws4 = *(const float4*)(w_s + lane * 4);
  float4 we4 = *(const float4*)(w_e + lane * 4);
  float bs0 = b_s[0], be0 = b_e[0];
  const float* en_b = en + (size_t)b * 40960;
  const float* vi_b = vi + (size_t)b * 40960;
  float q4[4] = {0.f,0.f,0.f,0.f}, v4[4] = {0.f,0.f,0.f,0.f};
  float wloc = 0.f;
  #pragma unroll
  for (int it = 0; it < 10; ++it) {
    int crow = wv * 10 + it;     // C: one row per wave per iter
    f32x4v ev = __builtin_nontemporal_load((const f32x4v*)(en_b + (size_t)crow * 256 + lane * 4));
    f32x4v vv = __builtin_nontemporal_load((const f32x4v*)(vi_b + (size_t)crow * 256 + lane * 4));
    if (actA) {
      int r = 16 * it + rm;      // A: uniform 16-row slab
      float4 g = *(const float4*)(gam_b + (size_t)r * 160 + 4 * c);
      f32x4v m = __builtin_nontemporal_load((const f32x4v*)(m_b + (size_t)r * 160 + 4 * c));
      wloc += m[0]*g.x + m[1]*g.y + m[2]*g.z + m[3]*g.w;
      S.prow[r][c] = g.x + g.y + g.z + g.w;
      q4[0]+=g.x; q4[1]+=g.y; q4[2]+=g.z; q4[3]+=g.w;
      float f = (r >= s && r <= e) ? 1.f : 0.f;
      v4[0]+=f*g.x; v4[1]+=f*g.y; v4[2]+=f*g.z; v4[3]+=f*g.w;
    }
    float a0 = ev[0]*ws4.x + ev[1]*ws4.y + ev[2]*ws4.z + ev[3]*ws4.w;
    float a1 = ev[0]*we4.x + ev[1]*we4.y + ev[2]*we4.z + ev[3]*we4.w;
    float a2 = vv[0]*ws4.x + vv[1]*ws4.y + vv[2]*ws4.z + vv[3]*ws4.w;
    float a3 = vv[0]*we4.x + vv[1]*we4.y + vv[2]*we4.z + vv[3]*we4.w;
    #pragma unroll
    for (int o = 32; o; o >>= 1) {
      a0 += __shfl_xor(a0, o); a1 += __shfl_xor(a1, o);
      a2 += __shfl_xor(a2, o); a3 += __shfl_xor(a3, o);
    }
    if (lane == 0) {
      S.esh[crow] = a0 + bs0;  S.eeh[crow] = a1 + be0;
      S.vssh[crow] = a2 + bs0; S.veh[crow] = a3 + be0;
    }
  }
  if (actA) {
    #pragma unroll
    for (int j = 0; j < 4; ++j) { S.qcol[rm][4*c+j] = q4[j]; S.vcol[rm][4*c+j] = v4[j]; }
  }
  #pragma unroll
  for (int o = 32; o; o >>= 1) wloc += __shfl_xor(wloc, o);
  if (lane == 0) S.wsh[wv] = wloc;
  __syncthreads();
  if (tid < 160) {
    float sp = 0.f;
    #pragma unroll 8
    for (int c2 = 0; c2 < 40; ++c2) sp += S.prow[tid][c2];
    psh_s[tid] = sp;
    float sq = 0.f, sv = 0.f;
    #pragma unroll 4
    for (int k = 0; k < 16; ++k) { sq += S.qcol[k][tid]; sv += S.vcol[k][tid]; }
    qsh_s[tid] = sq;
    S.vscsh[tid] = sv;
  }
  __syncthreads();

  // ---- Phase D: span argmax + QA CE + KL + span CE -> sp1[0..6] ----
  float best = -1e30f;
  int bfl = 0x7fffffff;
  if (tid < 160) {
    float vsi = S.vscsh[tid];
    int hi = min(tid + MAX_SPAN, Kn - 1);
    for (int ei = tid; ei <= hi; ++ei) {
      float v = vsi + S.vscsh[ei];
      if (v > best) { best = v; bfl = tid * Kn + ei; }  // first-max (np.argmax)
    }
  }
  if (tid < 256) { S.bv[tid] = best; S.bidx[tid] = bfl; }
  for (int st = 128; st > 0; st >>= 1) {
    __syncthreads();
    if (tid < st) {
      float v2 = S.bv[tid + st]; int i2 = S.bidx[tid + st];
      if (v2 > S.bv[tid] || (v2 == S.bv[tid] && i2 < S.bidx[tid])) { S.bv[tid] = v2; S.bidx[tid] = i2; }
    }
  }
  if (tid == 0) {
    int fl = S.bidx[0];
    int ps = fl / Kn, pe = fl - (fl / Kn) * Kn;
    if (s0 == 0 && e0 == 0) { ps = 0; pe = 0; }
    S.pspe[0] = ps; S.pspe[1] = pe;
    float sw = 0.f;
    #pragma unroll
    for (int i = 0; i < 16; ++i) sw += S.wsh[i];
    sp1[(size_t)b * 12 + 4] = sw;
  }
  __syncthreads();
  if (wv == 0) {
    float xes[3], xee[3], xvs[3], xve[3];
    #pragma unroll
    for (int j = 0; j < 3; ++j) {
      int idx = lane + 64 * j;
      bool val = idx < Kn;
      xes[j] = val ? S.esh[idx] : -1e30f;
      xee[j] = val ? S.eeh[idx] : -1e30f;
      xvs[j] = val ? S.vssh[idx] : -1e30f;
      xve[j] = val ? S.veh[idx] : -1e30f;
    }
    auto wlse = [&](float x0, float x1, float x2) -> float {
      float m = fmaxf(fmaxf(x0, x1), x2);
      #pragma unroll
      for (int o = 32; o; o >>= 1) m = fmaxf(m, __shfl_xor(m, o));
      float su = expf(x0 - m) + expf(x1 - m) + expf(x2 - m);
      #pragma unroll
      for (int o = 32; o; o >>= 1) su += __shfl_xor(su, o);
      return m + logf(su);
    };
    float l_es = wlse(xes[0], xes[1], xes[2]);
    float l_ee = wlse(xee[0], xee[1], xee[2]);
    float l_vs = wlse(xvs[0], xvs[1], xvs[2]);
    float l_ve = wlse(xve[0], xve[1], xve[2]);
    float lT_es = wlse(xes[0]*0.5f, xes[1]*0.5f, xes[2]*0.5f);
    float lT_ee = wlse(xee[0]*0.5f, xee[1]*0.5f, xee[2]*0.5f);
    float lT_vs = wlse(xvs[0]*0.5f, xvs[1]*0.5f, xvs[2]*0.5f);
    float lT_ve = wlse(xve[0]*0.5f, xve[1]*0.5f, xve[2]*0.5f);
    float kls = 0.f, kle = 0.f;
    #pragma unroll
    for (int j = 0; j < 3; ++j) {
      int idx = lane + 64 * j;
      if (idx < Kn) {
        float aa = xes[j]*0.5f - lT_es;
        float bb = xvs[j]*0.5f - lT_vs;
        kls += expf(aa) * (aa - bb);
        float cc = xee[j]*0.5f - lT_ee;
        float dd = xve[j]*0.5f - lT_ve;
        kle += expf(cc) * (cc - dd);
      }
    }
    #pragma unroll
    for (int o = 32; o; o >>= 1) { kls += __shfl_xor(kls, o); kle += __shfl_xor(kle, o); }
    if (lane == 0) {
      int sl = min(max(s0, 0), Kn - 1);
      int el = min(max(e0, 0), Kn - 1);
      float* o = sp1 + (size_t)b * 12;
      o[0] = l_es - S.esh[sl];
      o[1] = l_ee - S.eeh[el];
      o[2] = kls;
      o[3] = kle;
      bool answerable = (s0 > 0) || (e0 > 0);
      float ce = 0.5f * ((l_vs - S.vssh[S.pspe[0]]) + (l_ve - S.veh[S.pspe[1]]));
      o[5] = answerable ? ce : 0.f;
      o[6] = answerable ? 1.f : 0.f;
    }
  }
  __syncthreads();   // all Phase-D LDS reads done before fgw overwrites the union

  // ---- Phase E: fgw gw3 via MFMA; gw1/gw2 fused into the staging loads
  // (each D_en/D_vi element passes through exactly once, fp32, pre-bf16).
  bool rm0 = tid < 640;
  const float* s0p;
  __bf16 *d00, *d01;
  bool isDen0 = false, isVT0 = false;
  float w0r = 0.f;       // p[r] for D_en threads, q[j] for slot0-VT threads
  int cb0 = 0;           // 8*cc: column base within panel
  if (rm0) {
    int op = tid >= 320 ? 1 : 0;
    int fr = tid - 320 * op;
    int cc = fr >= 160 ? 1 : 0;
    int r = fr - 160 * cc;
    s0p = (op ? gam_b : den_b) + (size_t)r * 160 + 8 * cc;
    d00 = op ? &F.sG[0][cc][r][0] : &F.sDen[0][cc][r][0];
    d01 = op ? &F.sG[1][cc][r][0] : &F.sDen[1][cc][r][0];
    if (!op) { isDen0 = true; w0r = psh_s[r]; cb0 = 8 * cc; }
  } else {
    int f3 = tid - 640;
    int op = f3 >= 320 ? 1 : 0;
    int f4 = f3 - 320 * op;
    int cc = f4 >= 160 ? 1 : 0;
    int j = f4 - 160 * cc;
    s0p = (op ? dvi_b : gam_b) + (size_t)(8 * cc) * 160 + j;
    d00 = op ? &F.sVT[0][cc][j][0] : &F.sGT[0][cc][j][0];
    d01 = op ? &F.sVT[1][cc][j][0] : &F.sGT[1][cc][j][0];
    if (op) { isVT0 = true; w0r = qsh_s[j]; cb0 = 8 * cc; }
  }
  bool act1 = tid < 256;
  int f5 = tid + 64;
  int cc1 = f5 >= 160 ? 1 : 0;
  int j1 = f5 - 160 * cc1;
  const float* s1p = dvi_b + (size_t)(8 * cc1) * 160 + j1;
  __bf16* d10 = &F.sVT[0][cc1][j1][0];
  __bf16* d11 = &F.sVT[1][cc1][j1][0];
  float w1r = act1 ? qsh_s[j1] : 0.f;
  int cb1 = 8 * cc1;
  float gw1a = 0.f, gw2a = 0.f;

  float vA0[8], vA1[8], vB0[8], vB1[8];
  auto load0 = [&](int p, float* v) {
    if (rm0) {
      const float* sp = s0p + p * KP;
      float4 x = *(const float4*)sp;
      float4 y = *(const float4*)(sp + 4);
      v[0]=x.x; v[1]=x.y; v[2]=x.z; v[3]=x.w;
      v[4]=y.x; v[5]=y.y; v[6]=y.z; v[7]=y.w;
      if (isDen0) {
        const float* pw = psh_s + cb0 + 16 * p;
        float t = 0.f;
        #pragma unroll
        for (int e2 = 0; e2 < 8; ++e2) t += v[e2] * v[e2] * pw[e2];
        gw1a += w0r * t;
      }
    } else {
      const float* sp = s0p + (size_t)p * KP * 160;
      #pragma unroll
      for (int e2 = 0; e2 < 8; ++e2) v[e2] = sp[(size_t)e2 * 160];
      if (isVT0) {
        const float* qw = qsh_s + cb0 + 16 * p;
        float t = 0.f;
        #pragma unroll
        for (int e2 = 0; e2 < 8; ++e2) t += v[e2] * v[e2] * qw[e2];
        gw2a += w0r * t;
      }
    }
  };
  auto load1 = [&](int p, float* v) {
    if (!act1) return;
    const float* sp = s1p + (size_t)p * KP * 160;
    #pragma unroll
    for (int e2 = 0; e2 < 8; ++e2) v[e2] = sp[(size_t)e2 * 160];
    const float* qw = qsh_s + cb1 + 16 * p;
    float t = 0.f;
    #pragma unroll
    for (int e2 = 0; e2 < 8; ++e2) t += v[e2] * v[e2] * qw[e2];
    gw2a += w1r * t;
  };
  auto wr = [&](const float* v0, const float* v1, __bf16* w0, __bf16* w1) {
    bf16x8 wv2;
    #pragma unroll
    for (int e2 = 0; e2 < 8; ++e2) wv2[e2] = (__bf16)v0[e2];
    *(bf16x8*)w0 = wv2;
    if (act1) {
      bf16x8 wv3;
      #pragma unroll
      for (int e2 = 0; e2 < 8; ++e2) wv3[e2] = (__bf16)v1[e2];
      *(bf16x8*)w1 = wv3;
    }
  };

  int ra = lane & 31, cc2 = lane >> 5;
  int t0 = wv;                 // 0..15, always < 25
  int ti0 = t0 / 5, tj0 = t0 - 5 * (t0 / 5);
  int rowa0 = ti0 * 32 + ra, rowb0 = tj0 * 32 + ra;
  int t1 = wv + 16;
  bool val1t = t1 < 25;
  int ti1 = t1 / 5, tj1 = t1 - 5 * (t1 / 5);
  int rowa1 = ti1 * 32 + ra, rowb1 = tj1 * 32 + ra;
  f32x16 acc10 = {}, acc20 = {}, acc11 = {}, acc21 = {};
  auto mf = [&](int BUF) {
    {
      bf16x8 a1 = *(const bf16x8*)&F.sDen[BUF][cc2][rowa0][0];
      bf16x8 b1 = *(const bf16x8*)&F.sGT[BUF][cc2][rowb0][0];
      bf16x8 a2 = *(const bf16x8*)&F.sG[BUF][cc2][rowa0][0];
      bf16x8 b2 = *(const bf16x8*)&F.sVT[BUF][cc2][rowb0][0];
      acc10 = __builtin_amdgcn_mfma_f32_32x32x16_bf16(a1, b1, acc10, 0, 0, 0);
      acc20 = __builtin_amdgcn_mfma_f32_32x32x16_bf16(a2, b2, acc20, 0, 0, 0);
    }
    if (val1t) {
      bf16x8 a1 = *(const bf16x8*)&F.sDen[BUF][cc2][rowa1][0];
      bf16x8 b1 = *(const bf16x8*)&F.sGT[BUF][cc2][rowb1][0];
      bf16x8 a2 = *(const bf16x8*)&F.sG[BUF][cc2][rowa1][0];
      bf16x8 b2 = *(const bf16x8*)&F.sVT[BUF][cc2][rowb1][0];
      acc11 = __builtin_amdgcn_mfma_f32_32x32x16_bf16(a1, b1, acc11, 0, 0, 0);
      acc21 = __builtin_amdgcn_mfma_f32_32x32x16_bf16(a2, b2, acc21, 0, 0, 0);
    }
  };

  load0(0, vA0); load1(0, vA1);
  load0(1, vB0); load1(1, vB1);
  wr(vA0, vA1, d00, d10);
  __syncthreads();
  for (int p = 0; p < NP; p += 2) {
    if (p + 2 < NP) { load0(p + 2, vA0); load1(p + 2, vA1); }
    mf(0);
    wr(vB0, vB1, d01, d11);
    wg_barrier();
    if (p + 3 < NP) { load0(p + 3, vB0); load1(p + 3, vB1); }
    mf(1);
    if (p + 2 < NP) wr(vA0, vA1, d00, d10);
    wg_barrier();
  }
  float g3 = 0.f;
  #pragma unroll
  for (int r2 = 0; r2 < 16; ++r2) g3 += acc10[r2] * acc20[r2];
  if (val1t) {
    #pragma unroll
    for (int r2 = 0; r2 < 16; ++r2) g3 += acc11[r2] * acc21[r2];
  }
  #pragma unroll
  for (int o = 32; o; o >>= 1) {
    g3 += __shfl_xor(g3, o);
    gw1a += __shfl_xor(gw1a, o);
    gw2a += __shfl_xor(gw2a, o);
  }
  if (lane == 0) { F.red[wv] = g3; F.red[16 + wv] = gw1a; F.red[32 + wv] = gw2a; }
  __syncthreads();
  if (tid == 0) {
    float s3 = 0.f, s1 = 0.f, s2 = 0.f;
    #pragma unroll
    for (int i = 0; i < 16; ++i) { s3 += F.red[i]; s1 += F.red[16 + i]; s2 += F.red[32 + i]; }
    float* o = sp1 + (size_t)b * 12;
    o[7] = s1; o[8] = s2; o[9] = s3;
  }
}

// ---- final reduction over batches ----
__global__ __launch_bounds__(512) void finalize_k(
    const float* __restrict__ sp1, float* __restrict__ out) {
  __shared__ float red[8][10];
  int tid = threadIdx.x;
  int wid = tid >> 6, lane = tid & 63;
  float v[10];
  const float* a = sp1 + (size_t)tid * 12;
  #pragma unroll
  for (int i = 0; i < 10; ++i) v[i] = a[i];
  #pragma unroll
  for (int i = 0; i < 10; ++i) {
    float s = v[i];
    #pragma unroll
    for (int o = 32; o; o >>= 1) s += __shfl_xor(s, o);
    v[i] = s;
  }
  if (lane == 0) {
    #pragma unroll
    for (int i = 0; i < 10; ++i) red[wid][i] = v[i];
  }
  __syncthreads();
  if (tid == 0) {
    float t[10];
    #pragma unroll
    for (int i = 0; i < 10; ++i) {
      float s = 0.f;
      #pragma unroll
      for (int w2 = 0; w2 < 8; ++w2) s += red[w2][i];
      t[i] = s;
    }
    float ce_s = t[0], ce_e = t[1], kls = t[2], kle = t[3];
    float w = t[4], spn = t[5], nans = t[6];
    float gw1 = t[7], gw2 = t[8], gw3 = t[9];
    float l_qa = (ce_s + ce_e) / (2.f * Bn);
    float l_fgw = (ALPHA * (gw1 + gw2 - 2.f * gw3) + (1.f - ALPHA) * w) / Bn;
    float l_span = (nans > 0.f) ? spn / fmaxf(nans, 1.f) : 0.f;
    float l_cons = 2.f * (kls + kle) / Bn;  // T^2 * ((kls+kle)/B) / 2 with T=2
    float total = l_qa + L_FGW * l_fgw + L_SPAN * l_span + L_CONS * l_cons;
    out[0] = total; out[1] = l_qa; out[2] = l_fgw; out[3] = l_span; out[4] = l_cons;
  }
}

extern "C" void kernel_launch(void* const* d_in, const int* in_sizes, int n_in,
                              void* d_out, int out_size, void* d_ws, size_t ws_size,
                              hipStream_t stream) {
  const float* en  = (const float*)d_in[0];
  const float* vi  = (const float*)d_in[1];
  const float* gam = (const float*)d_in[2];
  const float* Den = (const float*)d_in[3];
  const float* Dvi = (const float*)d_in[4];
  const float* M   = (const float*)d_in[5];
  const int* enst  = (const int*)d_in[6];
  const int* enen  = (const int*)d_in[7];
  const float* w_s = (const float*)d_in[8];
  const float* b_s = (const float*)d_in[9];
  const float* w_e = (const float*)d_in[10];
  const float* b_e = (const float*)d_in[11];
  float* sp1 = (float*)d_ws;               // 512*12 per-batch partials
  float* out = (float*)d_out;

  mega_k<<<Bn, 1024, 0, stream>>>(en, vi, w_s, b_s, w_e, b_e, gam, M, Den, Dvi,
                                  enst, enen, sp1);
  finalize_k<<<1, 512, 0, stream>>>(sp1, out);
}